// Round 2
// baseline (3206.329 us; speedup 1.0000x reference)
//
#include <hip/hip_runtime.h>
#include <math.h>

#define N_NODES 250000
#define N_EDGES 2500000
#define N_GRAPHS 512
#define BN_EPS 1e-5f
#define NT 500000   // 2*N_NODES degree/offset slots (F then B)
#define INV_N (1.0f / (float)N_NODES)

// bf16 helpers (RNE); bf16->fp32 is an exact bit shift.
__device__ __forceinline__ unsigned short f2bf(float x) {
    unsigned int u = __float_as_uint(x);
    unsigned int r = (u + 0x7FFFu + ((u >> 16) & 1u)) >> 16;
    return (unsigned short)r;
}
__device__ __forceinline__ float bf2f(unsigned short b) {
    return __uint_as_float(((unsigned int)b) << 16);
}

// ================= CSR build (R0 structure: rank -> scan -> compact fill) ===
// R1 lesson: scatter into a SPARSE 44MB bucket footprint costs ~560 GB/s
// partial-line write-back churn (+260us). Compact 20MB CSR scatter is ~70us.

__global__ void k_rank(const int* __restrict__ src, const int* __restrict__ dst,
                       int* __restrict__ deg, int* __restrict__ rank, int E)
{
    int e = blockIdx.x * blockDim.x + threadIdx.x;
    if (e >= E) return;
    int rF = atomicAdd(&deg[dst[e]], 1);            // F lists keyed by dst
    int rB = atomicAdd(&deg[N_NODES + src[e]], 1);  // B lists keyed by src
    rank[e] = rF | (rB << 16);
}

__global__ void k_fill2(const int* __restrict__ src, const int* __restrict__ dst,
                        const int* __restrict__ off, const int* __restrict__ rank,
                        int* __restrict__ eidx, int E)
{
    int e = blockIdx.x * blockDim.x + threadIdx.x;
    if (e >= E) return;
    int s = src[e], d = dst[e];
    int r = rank[e];
    eidx[off[d] + (r & 0xFFFF)] = s;
    eidx[off[N_NODES + s] + (r >> 16)] = d;
}

__global__ void scan1(const int* __restrict__ deg, int* __restrict__ excl,
                      int* __restrict__ bsum, int n)
{
    __shared__ int s[256];
    int t = threadIdx.x, b = blockIdx.x;
    int base = b * 1024 + t * 4;
    int v[4]; int tsum = 0;
    #pragma unroll
    for (int i = 0; i < 4; i++) { v[i] = (base + i < n) ? deg[base + i] : 0; tsum += v[i]; }
    s[t] = tsum; __syncthreads();
    for (int o = 1; o < 256; o <<= 1) {
        int x = (t >= o) ? s[t - o] : 0; __syncthreads();
        s[t] += x; __syncthreads();
    }
    int run = s[t] - tsum;
    #pragma unroll
    for (int i = 0; i < 4; i++) { if (base + i < n) excl[base + i] = run; run += v[i]; }
    if (t == 255) bsum[b] = s[255];
}

__global__ void scan2(const int* __restrict__ bsum, int* __restrict__ boff, int nb)
{
    __shared__ int s[512];
    int t = threadIdx.x;
    int v = (t < nb) ? bsum[t] : 0;
    s[t] = v; __syncthreads();
    for (int o = 1; o < 512; o <<= 1) {
        int x = (t >= o) ? s[t - o] : 0; __syncthreads();
        s[t] += x; __syncthreads();
    }
    if (t < nb) boff[t] = s[t] - v;
}

__global__ void scan3(const int* __restrict__ excl, const int* __restrict__ boff,
                      int* __restrict__ off, int n)
{
    int i = blockIdx.x * blockDim.x + threadIdx.x;
    if (i < n) off[i] = excl[i] + boff[i >> 10];
    if (i == 0) off[n] = 2 * N_EDGES;
}

// ================= pad x (N x 6 fp32) -> xpad (N x 8 fp32) ==================

__global__ void pad_x(const float* __restrict__ x, float* __restrict__ xpad, int n)
{
    int i = blockIdx.x * blockDim.x + threadIdx.x;   // one float2 out per thread
    if (i >= n * 4) return;
    int node = i >> 2, p2 = i & 3;
    float2 v;
    v.x = (2 * p2     < 6) ? x[node * 6 + 2 * p2]     : 0.f;
    v.y = (2 * p2 + 1 < 6) ? x[node * 6 + 2 * p2 + 1] : 0.f;
    *(float2*)(xpad + node * 8 + 2 * p2) = v;
}

// ============ layer-1 gather, PACKED: 4 lanes x float2 per padded row =======

__global__ __launch_bounds__(256, 8)
void gather6p(const float* __restrict__ xpad, const int* __restrict__ off,
              const int* __restrict__ eidx, float* __restrict__ agg, int ngroups)
{
    int tid = threadIdx.x;
    int p2   = tid & 3;       // float2 index within row (cols 2p2, 2p2+1)
    int slot = tid >> 2;      // 0..63 node slots per block
    for (int grp = blockIdx.x; grp < ngroups; grp += gridDim.x) {
        int node = grp * 64 + slot;
        bool nvalid = (node < N_NODES);
        int nd = nvalid ? node : 0;
        #pragma unroll
        for (int dir = 0; dir < 2; dir++) {
            int u = dir * N_NODES + nd;
            int k0 = off[u], k1 = off[u + 1];
            if (!nvalid) k1 = k0;
            float a0=0.f,a1=0.f,b0=0.f,b1=0.f,c0=0.f,c1=0.f,d0=0.f,d1=0.f;
            for (int p = k0; p < k1; p += 8) {
                #pragma unroll
                for (int q = 0; q < 8; q++) {
                    int kk = p + q;
                    bool act = (kk < k1);
                    int j = eidx[act ? kk : k0];
                    float2 v = *(const float2*)(xpad + j * 8 + 2 * p2);
                    float lo = act ? v.x : 0.f;
                    float hi = act ? v.y : 0.f;
                    if ((q & 3) == 0)      { a0 += lo; a1 += hi; }
                    else if ((q & 3) == 1) { b0 += lo; b1 += hi; }
                    else if ((q & 3) == 2) { c0 += lo; c1 += hi; }
                    else                   { d0 += lo; d1 += hi; }
                }
            }
            if (nvalid && p2 < 3) {
                float2 s;
                s.x = (a0 + b0) + (c0 + d0);
                s.y = (a1 + b1) + (c1 + d1);
                *(float2*)(agg + nd * 12 + dir * 6 + 2 * p2) = s;
            }
        }
    }
}

// ========== FUSED gather + dual-dir GIN MLP + BN stats (layers 2/3) =========
// 16 lanes per node, 2 feats per lane (matches gather16's layout). The 32x32
// MLPs run 16-lane-cooperatively via __shfl(width=16) input broadcasts with
// weights in LDS (same-address across groups -> broadcast, conflict-free).
// FMA order identical to dgin_mlp2 -> bitwise-identical output. Removes the
// 64MB agg write + 64MB agg read + 16MB h re-read per layer and rides the MLP
// FLOPs in the gather's idle VALU slots. NOT in-place: hin != hout (neighbor
// rows of hin are read while hout is written).

__global__ __launch_bounds__(256, 8)
void dgin_fused(const unsigned short* __restrict__ hin,
                const int* __restrict__ off, const int* __restrict__ eidx,
                const float* __restrict__ in_stats,
                const float* __restrict__ in_g, const float* __restrict__ in_b,
                const float* __restrict__ W1f, const float* __restrict__ b1f,
                const float* __restrict__ W2f, const float* __restrict__ b2f,
                const float* __restrict__ W1b, const float* __restrict__ b1b,
                const float* __restrict__ W2b, const float* __restrict__ b2b,
                unsigned short* __restrict__ hout, float* __restrict__ stats,
                int ngroups)
{
    __shared__ __align__(16) float sW1[2][32 * 32];
    __shared__ __align__(16) float sW2[2][32 * 32];
    __shared__ float sb1[2][32], sb2[2][32];
    __shared__ float sscale[32], sshift[32];
    __shared__ float sstat[64];

    int tid = threadIdx.x;
    for (int i = tid; i < 32 * 32; i += 256) {
        sW1[0][i] = W1f[i]; sW1[1][i] = W1b[i];
        sW2[0][i] = W2f[i]; sW2[1][i] = W2b[i];
    }
    if (tid < 32) {
        sb1[0][tid] = b1f[tid]; sb1[1][tid] = b1b[tid];
        sb2[0][tid] = b2f[tid]; sb2[1][tid] = b2b[tid];
        float mu  = in_stats[tid] * INV_N;
        float var = in_stats[32 + tid] * INV_N - mu * mu;
        float sc  = in_g[tid] * rsqrtf(var + BN_EPS);
        sscale[tid] = sc;
        sshift[tid] = in_b[tid] - mu * sc;
    }
    if (tid < 64) sstat[tid] = 0.f;
    __syncthreads();

    const unsigned int* xu = (const unsigned int*)hin;   // row = 16 uints
    unsigned int* ou = (unsigned int*)hout;
    int fp = tid & 15;
    int f0 = 2 * fp, f1 = 2 * fp + 1;
    int gg = tid >> 4;

    float ss0 = 0.f, ss1 = 0.f, sq0 = 0.f, sq1 = 0.f;  // per-lane stats acc

    for (int grp = blockIdx.x; grp < ngroups; grp += gridDim.x) {
        int node = grp * 16 + gg;

        // self row (2 feats of this lane)
        unsigned int sv = xu[node * 16 + fp];
        float selfx = __uint_as_float(sv << 16);
        float selfy = __uint_as_float(sv & 0xFFFF0000u);

        float ox = 0.f, oy = 0.f;

        #pragma unroll
        for (int dir = 0; dir < 2; dir++) {
            int u = dir * N_NODES + node;
            int k0 = off[u], k1 = off[u + 1];

            // ---- gather (8-deep miss queue, identical to gather16) ----
            float a0 = 0.f, a1 = 0.f, b0 = 0.f, b1 = 0.f;
            float c0 = 0.f, c1 = 0.f, d0 = 0.f, d1 = 0.f;
            for (int p = k0; p < k1; p += 8) {
                #pragma unroll
                for (int q = 0; q < 8; q++) {
                    int kk = p + q;
                    bool act = (kk < k1);
                    int j = eidx[act ? kk : k0];
                    unsigned int v = xu[j * 16 + fp];
                    float lo = act ? __uint_as_float(v << 16) : 0.f;
                    float hi = act ? __uint_as_float(v & 0xFFFF0000u) : 0.f;
                    if ((q & 3) == 0)      { a0 += lo; a1 += hi; }
                    else if ((q & 3) == 1) { b0 += lo; b1 += hi; }
                    else if ((q & 3) == 2) { c0 += lo; c1 += hi; }
                    else                   { d0 += lo; d1 += hi; }
                }
            }
            float sx = (a0 + b0) + (c0 + d0);
            float sy = (a1 + b1) + (c1 + d1);

            // ---- h = x + agg, then input-BN (same fmaf form as dgin_mlp2) --
            float degp1 = (float)(k1 - k0 + 1);
            float hx = selfx + sx;
            float hy = selfy + sy;
            hx = fmaf(sscale[f0], hx, degp1 * sshift[f0]);
            hy = fmaf(sscale[f1], hy, degp1 * sshift[f1]);

            // ---- MLP layer 1: t1[f0,f1] = b1 + sum_i h_i * W1[i][f] -------
            float t1x = sb1[dir][f0], t1y = sb1[dir][f1];
            #pragma unroll
            for (int ii = 0; ii < 16; ii++) {
                float gx = __shfl(hx, ii, 16);   // input feat 2*ii
                float gy = __shfl(hy, ii, 16);   // input feat 2*ii+1
                float2 wx = *(const float2*)(&sW1[dir][(2 * ii) * 32 + f0]);
                float2 wy = *(const float2*)(&sW1[dir][(2 * ii + 1) * 32 + f0]);
                t1x = fmaf(gx, wx.x, t1x); t1y = fmaf(gx, wx.y, t1y);
                t1x = fmaf(gy, wy.x, t1x); t1y = fmaf(gy, wy.y, t1y);
            }
            t1x = fmaxf(t1x, 0.f); t1y = fmaxf(t1y, 0.f);

            // ---- MLP layer 2 ----
            float o2x = sb2[dir][f0], o2y = sb2[dir][f1];
            #pragma unroll
            for (int ii = 0; ii < 16; ii++) {
                float gx = __shfl(t1x, ii, 16);
                float gy = __shfl(t1y, ii, 16);
                float2 wx = *(const float2*)(&sW2[dir][(2 * ii) * 32 + f0]);
                float2 wy = *(const float2*)(&sW2[dir][(2 * ii + 1) * 32 + f0]);
                o2x = fmaf(gx, wx.x, o2x); o2y = fmaf(gx, wx.y, o2y);
                o2x = fmaf(gy, wy.x, o2x); o2y = fmaf(gy, wy.y, o2y);
            }
            if (dir == 0) {
                ox = fmaxf(o2x, 0.f); oy = fmaxf(o2y, 0.f);
            } else {
                ox = 0.5f * (ox + fmaxf(o2x, 0.f));
                oy = 0.5f * (oy + fmaxf(o2y, 0.f));
            }
        }

        // round once to bf16; stats accumulate the ROUNDED value
        unsigned short bx = f2bf(ox), by = f2bf(oy);
        ox = bf2f(bx); oy = bf2f(by);
        ou[node * 16 + fp] = (unsigned int)bx | ((unsigned int)by << 16);

        ss0 += ox; sq0 += ox * ox;
        ss1 += oy; sq1 += oy * oy;
    }

    // reduce the 4 node-groups of each wave (lanes i, i+16, i+32, i+48)
    ss0 += __shfl_down(ss0, 16); ss0 += __shfl_down(ss0, 32);
    ss1 += __shfl_down(ss1, 16); ss1 += __shfl_down(ss1, 32);
    sq0 += __shfl_down(sq0, 16); sq0 += __shfl_down(sq0, 32);
    sq1 += __shfl_down(sq1, 16); sq1 += __shfl_down(sq1, 32);
    if ((tid & 63) < 16) {
        atomicAdd(&sstat[f0], ss0);
        atomicAdd(&sstat[f1], ss1);
        atomicAdd(&sstat[32 + f0], sq0);
        atomicAdd(&sstat[32 + f1], sq1);
    }
    __syncthreads();
    if (tid < 64) atomicAdd(&stats[tid], sstat[tid]);
}

// ================= thread-per-node GIN MLP + BN stats (layer 1 only) ========

template <int DIN, bool BN_IN, bool IN_BF16>
__global__ __launch_bounds__(256, 1)
void dgin_mlp2(const void* __restrict__ xin_v, const float* __restrict__ agg,
               const int* __restrict__ off,
               const float* __restrict__ in_stats,
               const float* __restrict__ in_g, const float* __restrict__ in_b,
               const float* __restrict__ W1f, const float* __restrict__ b1f,
               const float* __restrict__ W2f, const float* __restrict__ b2f,
               const float* __restrict__ W1b, const float* __restrict__ b1b,
               const float* __restrict__ W2b, const float* __restrict__ b2b,
               unsigned short* __restrict__ out, float* __restrict__ stats, int n)
{
    const float* xf = (const float*)xin_v;
    const unsigned short* xb = (const unsigned short*)xin_v;

    __shared__ __align__(16) float sW1[2][DIN * 32];
    __shared__ __align__(16) float sW2[2][32 * 32];
    __shared__ float sb1[2][32], sb2[2][32];
    __shared__ float sscale[32], sshift[32];
    __shared__ float sred[4 * 64];

    int tid = threadIdx.x;
    for (int i = tid; i < DIN * 32; i += 256) { sW1[0][i] = W1f[i]; sW1[1][i] = W1b[i]; }
    for (int i = tid; i < 32 * 32;  i += 256) { sW2[0][i] = W2f[i]; sW2[1][i] = W2b[i]; }
    if (tid < 32) {
        sb1[0][tid] = b1f[tid]; sb1[1][tid] = b1b[tid];
        sb2[0][tid] = b2f[tid]; sb2[1][tid] = b2b[tid];
        if (BN_IN) {
            float mu  = in_stats[tid] * INV_N;
            float var = in_stats[32 + tid] * INV_N - mu * mu;
            float sc  = in_g[tid] * rsqrtf(var + BN_EPS);
            sscale[tid] = sc;
            sshift[tid] = in_b[tid] - mu * sc;
        } else { sscale[tid] = 1.f; sshift[tid] = 0.f; }
    }
    __syncthreads();

    int n0 = blockIdx.x * 256 + tid;
    bool valid = (n0 < n);
    int node = valid ? n0 : (n - 1);

    // self row
    float xr[DIN];
    if (IN_BF16) {
        const uint4* xp = (const uint4*)(xb + node * 32);
        #pragma unroll
        for (int q = 0; q < 4; q++) {
            uint4 u = xp[q];
            unsigned int w[4] = {u.x, u.y, u.z, u.w};
            #pragma unroll
            for (int k = 0; k < 4; k++) {
                xr[8*q + 2*k]     = __uint_as_float(w[k] << 16);
                xr[8*q + 2*k + 1] = __uint_as_float(w[k] & 0xFFFF0000u);
            }
        }
    } else if (DIN == 32) {
        const float4* xp = (const float4*)(xf + node * 32);
        #pragma unroll
        for (int q = 0; q < 8; q++) {
            float4 w = xp[q];
            xr[4*q+0] = w.x; xr[4*q+1] = w.y; xr[4*q+2] = w.z; xr[4*q+3] = w.w;
        }
    } else {
        const float2* xp = (const float2*)(xf + node * DIN);
        #pragma unroll
        for (int q = 0; q < DIN / 2; q++) {
            float2 w = xp[q];
            xr[2*q+0] = w.x; xr[2*q+1] = w.y;
        }
    }

    float o[32];

    #pragma unroll
    for (int dir = 0; dir < 2; dir++) {
        float ag[DIN];
        if (DIN == 32) {
            const float4* ap = (const float4*)(agg + node * 64 + dir * 32);
            #pragma unroll
            for (int q = 0; q < 8; q++) {
                float4 w = ap[q];
                ag[4*q+0] = w.x; ag[4*q+1] = w.y; ag[4*q+2] = w.z; ag[4*q+3] = w.w;
            }
        } else {
            const float* ap = agg + node * (2 * DIN) + dir * DIN;
            #pragma unroll
            for (int i = 0; i < DIN; i++) ag[i] = ap[i];
        }
        int ob = dir * N_NODES + node;
        float degp1 = (float)(off[ob + 1] - off[ob] + 1);

        float t1[32];
        #pragma unroll
        for (int j = 0; j < 32; j++) t1[j] = sb1[dir][j];
        #pragma unroll
        for (int i = 0; i < DIN; i++) {
            float hv = xr[i] + ag[i];
            if (BN_IN) hv = fmaf(sscale[i], hv, degp1 * sshift[i]);
            const float4* wr = (const float4*)(&sW1[dir][i * 32]);
            #pragma unroll
            for (int q = 0; q < 8; q++) {
                float4 w = wr[q];
                t1[4*q+0] = fmaf(hv, w.x, t1[4*q+0]);
                t1[4*q+1] = fmaf(hv, w.y, t1[4*q+1]);
                t1[4*q+2] = fmaf(hv, w.z, t1[4*q+2]);
                t1[4*q+3] = fmaf(hv, w.w, t1[4*q+3]);
            }
        }
        #pragma unroll
        for (int j = 0; j < 32; j++) t1[j] = fmaxf(t1[j], 0.f);

        float o2[32];
        #pragma unroll
        for (int j = 0; j < 32; j++) o2[j] = sb2[dir][j];
        #pragma unroll
        for (int i = 0; i < 32; i++) {
            float hv = t1[i];
            const float4* wr = (const float4*)(&sW2[dir][i * 32]);
            #pragma unroll
            for (int q = 0; q < 8; q++) {
                float4 w = wr[q];
                o2[4*q+0] = fmaf(hv, w.x, o2[4*q+0]);
                o2[4*q+1] = fmaf(hv, w.y, o2[4*q+1]);
                o2[4*q+2] = fmaf(hv, w.z, o2[4*q+2]);
                o2[4*q+3] = fmaf(hv, w.w, o2[4*q+3]);
            }
        }
        if (dir == 0) {
            #pragma unroll
            for (int j = 0; j < 32; j++) o[j] = fmaxf(o2[j], 0.f);
        } else {
            #pragma unroll
            for (int j = 0; j < 32; j++) o[j] = 0.5f * (o[j] + fmaxf(o2[j], 0.f));
        }
    }

    // round once to bf16; stats accumulate the ROUNDED value
    #pragma unroll
    for (int j = 0; j < 32; j++) o[j] = bf2f(f2bf(o[j]));

    if (valid) {
        uint4* op = (uint4*)(out + node * 32);
        #pragma unroll
        for (int q = 0; q < 4; q++) {
            uint4 u;
            u.x = (unsigned int)f2bf(o[8*q+0]) | ((unsigned int)f2bf(o[8*q+1]) << 16);
            u.y = (unsigned int)f2bf(o[8*q+2]) | ((unsigned int)f2bf(o[8*q+3]) << 16);
            u.z = (unsigned int)f2bf(o[8*q+4]) | ((unsigned int)f2bf(o[8*q+5]) << 16);
            u.w = (unsigned int)f2bf(o[8*q+6]) | ((unsigned int)f2bf(o[8*q+7]) << 16);
            op[q] = u;
        }
    }

    int lane = tid & 63;
    int wave = tid >> 6;
    #pragma unroll
    for (int f = 0; f < 32; f++) {
        float v = valid ? o[f] : 0.f;
        float v2 = v * v;
        #pragma unroll
        for (int offs = 32; offs > 0; offs >>= 1) {
            v  += __shfl_down(v, offs);
            v2 += __shfl_down(v2, offs);
        }
        if (lane == 0) {
            sred[wave * 64 + f]      = v;
            sred[wave * 64 + 32 + f] = v2;
        }
    }
    __syncthreads();
    if (tid < 64) {
        float a = sred[tid] + sred[64 + tid] + sred[128 + tid] + sred[192 + tid];
        atomicAdd(&stats[tid], a);
    }
}

// ================= segmented mean-pool (batch is sorted) + head =============

__global__ void pool_seg(const unsigned short* __restrict__ h, const int* __restrict__ batch,
                         float* __restrict__ psum, float* __restrict__ pcnt, int n)
{
    int tid = threadIdx.x;
    int grp = tid >> 5, f = tid & 31;
    int base = blockIdx.x * 256;
    float acc = 0.f, cnt = 0.f;
    int curg = -1;
    for (int it = 0; it < 32; it++) {
        int nd = base + grp + it * 8;
        if (nd < n) {
            int g = batch[nd];
            if (g != curg) {
                if (curg >= 0) {
                    atomicAdd(&psum[curg * 32 + f], acc);
                    if (f == 0) atomicAdd(&pcnt[curg], cnt);
                }
                curg = g; acc = 0.f; cnt = 0.f;
            }
            acc += bf2f(h[nd * 32 + f]);
            cnt += 1.f;
        }
    }
    if (curg >= 0) {
        atomicAdd(&psum[curg * 32 + f], acc);
        if (f == 0) atomicAdd(&pcnt[curg], cnt);
    }
}

__global__ void head_kernel(const float* __restrict__ psum, const float* __restrict__ pcnt,
                            const float* __restrict__ stats3,
                            const float* __restrict__ g3, const float* __restrict__ b3,
                            const float* __restrict__ lbW, const float* __restrict__ lbb,
                            const float* __restrict__ lmW, const float* __restrict__ lmb,
                            float* __restrict__ out)
{
    int g = threadIdx.x;  // 512 threads, one block
    float cnt = fmaxf(pcnt[g], 1.0f);
    float inv = 1.0f / cnt;
    float p[32];
    #pragma unroll
    for (int i = 0; i < 32; i++) {
        float mu  = stats3[i] * INV_N;
        float var = stats3[32 + i] * INV_N - mu * mu;
        float a   = g3[i] * rsqrtf(var + BN_EPS);
        float b   = b3[i] - mu * a;
        p[i] = fmaf(a, psum[g * 32 + i] * inv, b);
    }
    float z = lmb[0];
    #pragma unroll
    for (int k = 0; k < 16; k++) {
        float acc = lbb[k];
        #pragma unroll
        for (int i = 0; i < 32; i++) acc += p[i] * lbW[i * 16 + k];
        z += fmaxf(acc, 0.0f) * lmW[k];
    }
    out[g] = 1.0f / (1.0f + expf(-z));
}

// ================= launcher =================================================

extern "C" void kernel_launch(void* const* d_in, const int* in_sizes, int n_in,
                              void* d_out, int out_size, void* d_ws, size_t ws_size,
                              hipStream_t stream)
{
    const float* x   = (const float*)d_in[0];
    const int* ei    = (const int*)d_in[1];
    const int* batch = (const int*)d_in[2];
    const int* src = ei;
    const int* dst = ei + N_EDGES;
    char* ws = (char*)d_ws;

    auto W = [&](int l, int j) { return (const float*)d_in[3 + (l - 1) * 10 + j]; };

    // ---------------- layout (R0 layout; h2 lives in the dead agg region) ---
    unsigned short* h = (unsigned short*)(ws + 0);   // 16 MB (bf16 N x 32)
    float* xpad = (float*)(ws + 16000016);     // 8 MB (N x 8 fp32, padded x)
    float* agg  = (float*)(ws + 32000000);     // layer-1 agg: N x 12 fp32 (12 MB)
    int*   eidx = (int*)  (ws + 96000000);     // 20 MB
    int*   off  = (int*)  (ws + 116000000);    // (NT+1) ints
    // CSR-build temps live inside the agg region (dead until first gather)
    int*   deg   = (int*)  (ws + 32000000);    // 2 MB
    int*   excl  = (int*)  (ws + 34000016);    // 2 MB
    int*   bsum  = (int*)  (ws + 36000016);    // ~2 KB
    int*   boff  = (int*)  (ws + 36004016);    // ~2 KB
    int*   rank  = (int*)  (ws + 38000016);    // 10 MB packed rF|rB<<16
    // double-buffer for fused layers (after rank end 48,000,016; agg region
    // 32M..96M is unused past node*12 = 44 MB for layer 1)
    unsigned short* h2 = (unsigned short*)(ws + 48000016);  // 16 MB
    float* stats1 = (float*)(ws + 118000016);
    float* stats2 = stats1 + 64;
    float* stats3 = stats1 + 128;
    float* psum   = (float*)(ws + 118000784);
    float* pcnt   = (float*)(ws + 118066320);

    // ---- CSR build: rank pass (atomics) -> scan -> atomic-free compact fill
    hipMemsetAsync(deg, 0, NT * 4, stream);
    k_rank<<<(N_EDGES + 255) / 256, 256, 0, stream>>>(src, dst, deg, rank, N_EDGES);
    int nb = (NT + 1023) / 1024;
    scan1<<<nb, 256, 0, stream>>>(deg, excl, bsum, NT);
    scan2<<<1, 512, 0, stream>>>(bsum, boff, nb);
    scan3<<<(NT + 256) / 256, 256, 0, stream>>>(excl, boff, off, NT);
    k_fill2<<<(N_EDGES + 255) / 256, 256, 0, stream>>>(src, dst, off, rank, eidx, N_EDGES);

    pad_x<<<(N_NODES * 4 + 255) / 256, 256, 0, stream>>>(x, xpad, N_NODES);
    hipMemsetAsync(stats1, 0, 3 * 64 * 4, stream);

    const int GG   = 4096;
    const int NG64 = (N_NODES + 63) / 64;    // 3907 groups (packed layer-1)
    const int NG16 = N_NODES / 16;           // 15625 groups (exact)
    const int GM   = (N_NODES + 255) / 256;  // 977 mlp blocks (thread-per-node)
    const int GF   = 2048;                   // fused grid (8 blocks/CU)

    // layer 1 (DIN=6): packed gather on xpad; mlp reads original fp32 x
    gather6p<<<GG, 256, 0, stream>>>(xpad, off, eidx, agg, NG64);
    dgin_mlp2<6, false, false><<<GM, 256, 0, stream>>>(
        x, agg, off, nullptr, nullptr, nullptr,
        W(1,0), W(1,1), W(1,2), W(1,3), W(1,4), W(1,5), W(1,6), W(1,7),
        h, stats1, N_NODES);

    // layer 2: fused gather+MLP, h -> h2
    dgin_fused<<<GF, 256, 0, stream>>>(
        h, off, eidx, stats1, W(1,8), W(1,9),
        W(2,0), W(2,1), W(2,2), W(2,3), W(2,4), W(2,5), W(2,6), W(2,7),
        h2, stats2, NG16);

    // layer 3: fused gather+MLP, h2 -> h
    dgin_fused<<<GF, 256, 0, stream>>>(
        h2, off, eidx, stats2, W(2,8), W(2,9),
        W(3,0), W(3,1), W(3,2), W(3,3), W(3,4), W(3,5), W(3,6), W(3,7),
        h, stats3, NG16);

    hipMemsetAsync(psum, 0, (size_t)N_GRAPHS * 32 * 4, stream);
    hipMemsetAsync(pcnt, 0, (size_t)N_GRAPHS * 4, stream);
    pool_seg<<<(N_NODES + 255) / 256, 256, 0, stream>>>(h, batch, psum, pcnt, N_NODES);
    head_kernel<<<1, 512, 0, stream>>>(psum, pcnt, stats3, W(3,8), W(3,9),
        (const float*)d_in[33], (const float*)d_in[34],
        (const float*)d_in[35], (const float*)d_in[36],
        (float*)d_out);
}

// Round 3
// 1959.621 us; speedup vs baseline: 1.6362x; 1.6362x over previous
//
#include <hip/hip_runtime.h>
#include <math.h>

#define N_NODES 250000
#define N_EDGES 2500000
#define N_GRAPHS 512
#define BN_EPS 1e-5f
#define NT 500000   // 2*N_NODES degree/offset slots (F then B)
#define INV_N (1.0f / (float)N_NODES)

// bf16 helpers (RNE); bf16->fp32 is an exact bit shift.
__device__ __forceinline__ unsigned short f2bf(float x) {
    unsigned int u = __float_as_uint(x);
    unsigned int r = (u + 0x7FFFu + ((u >> 16) & 1u)) >> 16;
    return (unsigned short)r;
}
__device__ __forceinline__ float bf2f(unsigned short b) {
    return __uint_as_float(((unsigned int)b) << 16);
}

// ================= CSR build (R0 structure: rank -> scan -> compact fill) ===
// R1 lesson: sparse bucket scatter churns partial-line writebacks (+260us).
// Compact CSR scatter is cheap. k_rank's 5M atomic-returns are the floor.

__global__ void k_rank(const int* __restrict__ src, const int* __restrict__ dst,
                       int* __restrict__ deg, int* __restrict__ rank, int E)
{
    int e = blockIdx.x * blockDim.x + threadIdx.x;
    if (e >= E) return;
    int rF = atomicAdd(&deg[dst[e]], 1);            // F lists keyed by dst
    int rB = atomicAdd(&deg[N_NODES + src[e]], 1);  // B lists keyed by src
    rank[e] = rF | (rB << 16);
}

__global__ void k_fill2(const int* __restrict__ src, const int* __restrict__ dst,
                        const int* __restrict__ off, const int* __restrict__ rank,
                        int* __restrict__ eidx, int E)
{
    int e = blockIdx.x * blockDim.x + threadIdx.x;
    if (e >= E) return;
    int s = src[e], d = dst[e];
    int r = rank[e];
    eidx[off[d] + (r & 0xFFFF)] = s;
    eidx[off[N_NODES + s] + (r >> 16)] = d;
}

__global__ void scan1(const int* __restrict__ deg, int* __restrict__ excl,
                      int* __restrict__ bsum, int n)
{
    __shared__ int s[256];
    int t = threadIdx.x, b = blockIdx.x;
    int base = b * 1024 + t * 4;
    int v[4]; int tsum = 0;
    #pragma unroll
    for (int i = 0; i < 4; i++) { v[i] = (base + i < n) ? deg[base + i] : 0; tsum += v[i]; }
    s[t] = tsum; __syncthreads();
    for (int o = 1; o < 256; o <<= 1) {
        int x = (t >= o) ? s[t - o] : 0; __syncthreads();
        s[t] += x; __syncthreads();
    }
    int run = s[t] - tsum;
    #pragma unroll
    for (int i = 0; i < 4; i++) { if (base + i < n) excl[base + i] = run; run += v[i]; }
    if (t == 255) bsum[b] = s[255];
}

__global__ void scan2(const int* __restrict__ bsum, int* __restrict__ boff, int nb)
{
    __shared__ int s[512];
    int t = threadIdx.x;
    int v = (t < nb) ? bsum[t] : 0;
    s[t] = v; __syncthreads();
    for (int o = 1; o < 512; o <<= 1) {
        int x = (t >= o) ? s[t - o] : 0; __syncthreads();
        s[t] += x; __syncthreads();
    }
    if (t < nb) boff[t] = s[t] - v;
}

__global__ void scan3(const int* __restrict__ excl, const int* __restrict__ boff,
                      int* __restrict__ off, int n)
{
    int i = blockIdx.x * blockDim.x + threadIdx.x;
    if (i < n) off[i] = excl[i] + boff[i >> 10];
    if (i == 0) off[n] = 2 * N_EDGES;
}

// ================= pad x (N x 6 fp32) -> xpad (N x 8 fp32) ==================

__global__ void pad_x(const float* __restrict__ x, float* __restrict__ xpad, int n)
{
    int i = blockIdx.x * blockDim.x + threadIdx.x;   // one float2 out per thread
    if (i >= n * 4) return;
    int node = i >> 2, p2 = i & 3;
    float2 v;
    v.x = (2 * p2     < 6) ? x[node * 6 + 2 * p2]     : 0.f;
    v.y = (2 * p2 + 1 < 6) ? x[node * 6 + 2 * p2 + 1] : 0.f;
    *(float2*)(xpad + node * 8 + 2 * p2) = v;
}

// ============ layer-1 gather, PACKED: 4 lanes x float2 per padded row =======

__global__ __launch_bounds__(256, 8)
void gather6p(const float* __restrict__ xpad, const int* __restrict__ off,
              const int* __restrict__ eidx, float* __restrict__ agg, int ngroups)
{
    int tid = threadIdx.x;
    int p2   = tid & 3;       // float2 index within row (cols 2p2, 2p2+1)
    int slot = tid >> 2;      // 0..63 node slots per block
    for (int grp = blockIdx.x; grp < ngroups; grp += gridDim.x) {
        int node = grp * 64 + slot;
        bool nvalid = (node < N_NODES);
        int nd = nvalid ? node : 0;
        #pragma unroll
        for (int dir = 0; dir < 2; dir++) {
            int u = dir * N_NODES + nd;
            int k0 = off[u], k1 = off[u + 1];
            if (!nvalid) k1 = k0;
            float a0=0.f,a1=0.f,b0=0.f,b1=0.f,c0=0.f,c1=0.f,d0=0.f,d1=0.f;
            for (int p = k0; p < k1; p += 8) {
                #pragma unroll
                for (int q = 0; q < 8; q++) {
                    int kk = p + q;
                    bool act = (kk < k1);
                    int j = eidx[act ? kk : k0];
                    float2 v = *(const float2*)(xpad + j * 8 + 2 * p2);
                    float lo = act ? v.x : 0.f;
                    float hi = act ? v.y : 0.f;
                    if ((q & 3) == 0)      { a0 += lo; a1 += hi; }
                    else if ((q & 3) == 1) { b0 += lo; b1 += hi; }
                    else if ((q & 3) == 2) { c0 += lo; c1 += hi; }
                    else                   { d0 += lo; d1 += hi; }
                }
            }
            if (nvalid && p2 < 3) {
                float2 s;
                s.x = (a0 + b0) + (c0 + d0);
                s.y = (a1 + b1) + (c1 + d1);
                *(float2*)(agg + nd * 12 + dir * 6 + 2 * p2) = s;
            }
        }
    }
}

// ================= bf16 gather (DIN=32): ushort2 per lane, 16 lanes/row =====

__global__ __launch_bounds__(256, 8)
void gather16(const unsigned short* __restrict__ xb, const int* __restrict__ off,
              const int* __restrict__ eidx, float* __restrict__ agg, int ngroups)
{
    const unsigned int* xu = (const unsigned int*)xb;   // row = 16 uints
    int tid = threadIdx.x;
    int fp = tid & 15;
    int gg = tid >> 4;
    for (int grp = blockIdx.x; grp < ngroups; grp += gridDim.x) {
        int node = grp * 16 + gg;
        #pragma unroll
        for (int dir = 0; dir < 2; dir++) {
            int u = dir * N_NODES + node;
            int k0 = off[u], k1 = off[u + 1];
            float a0 = 0.f, a1 = 0.f, b0 = 0.f, b1 = 0.f;
            float c0 = 0.f, c1 = 0.f, d0 = 0.f, d1 = 0.f;
            for (int p = k0; p < k1; p += 8) {
                #pragma unroll
                for (int q = 0; q < 8; q++) {
                    int kk = p + q;
                    bool act = (kk < k1);
                    int j = eidx[act ? kk : k0];
                    unsigned int v = xu[j * 16 + fp];
                    float lo = act ? __uint_as_float(v << 16) : 0.f;
                    float hi = act ? __uint_as_float(v & 0xFFFF0000u) : 0.f;
                    if ((q & 3) == 0)      { a0 += lo; a1 += hi; }
                    else if ((q & 3) == 1) { b0 += lo; b1 += hi; }
                    else if ((q & 3) == 2) { c0 += lo; c1 += hi; }
                    else                   { d0 += lo; d1 += hi; }
                }
            }
            float2 s;
            s.x = (a0 + b0) + (c0 + d0);
            s.y = (a1 + b1) + (c1 + d1);
            *(float2*)(agg + node * 64 + dir * 32 + 2 * fp) = s;
        }
    }
}

// ========== FUSED gather + dual-dir GIN MLP + BN stats (layer 3 A/B) ========
// R2's version spilled to scratch under __launch_bounds__(256,8)'s 64-VGPR
// budget (FETCH 2.75GB / WRITE 789MB of hidden scratch traffic, 6% VALUBusy).
// Fix under test: (256,4) -> 128-VGPR budget; ~50-60 live peak -> no spill.
// Math identical to R2 (absmax was unchanged there): 16 lanes/node, 2 feats/
// lane, __shfl(width=16) input broadcasts, weights in LDS (broadcast reads).

__global__ __launch_bounds__(256, 4)
void dgin_fused(const unsigned short* __restrict__ hin,
                const int* __restrict__ off, const int* __restrict__ eidx,
                const float* __restrict__ in_stats,
                const float* __restrict__ in_g, const float* __restrict__ in_b,
                const float* __restrict__ W1f, const float* __restrict__ b1f,
                const float* __restrict__ W2f, const float* __restrict__ b2f,
                const float* __restrict__ W1b, const float* __restrict__ b1b,
                const float* __restrict__ W2b, const float* __restrict__ b2b,
                unsigned short* __restrict__ hout, float* __restrict__ stats,
                int ngroups)
{
    __shared__ __align__(16) float sW1[2][32 * 32];
    __shared__ __align__(16) float sW2[2][32 * 32];
    __shared__ float sb1[2][32], sb2[2][32];
    __shared__ float sscale[32], sshift[32];
    __shared__ float sstat[64];

    int tid = threadIdx.x;
    for (int i = tid; i < 32 * 32; i += 256) {
        sW1[0][i] = W1f[i]; sW1[1][i] = W1b[i];
        sW2[0][i] = W2f[i]; sW2[1][i] = W2b[i];
    }
    if (tid < 32) {
        sb1[0][tid] = b1f[tid]; sb1[1][tid] = b1b[tid];
        sb2[0][tid] = b2f[tid]; sb2[1][tid] = b2b[tid];
        float mu  = in_stats[tid] * INV_N;
        float var = in_stats[32 + tid] * INV_N - mu * mu;
        float sc  = in_g[tid] * rsqrtf(var + BN_EPS);
        sscale[tid] = sc;
        sshift[tid] = in_b[tid] - mu * sc;
    }
    if (tid < 64) sstat[tid] = 0.f;
    __syncthreads();

    const unsigned int* xu = (const unsigned int*)hin;   // row = 16 uints
    unsigned int* ou = (unsigned int*)hout;
    int fp = tid & 15;
    int f0 = 2 * fp, f1 = 2 * fp + 1;
    int gg = tid >> 4;

    float ss0 = 0.f, ss1 = 0.f, sq0 = 0.f, sq1 = 0.f;  // per-lane stats acc

    for (int grp = blockIdx.x; grp < ngroups; grp += gridDim.x) {
        int node = grp * 16 + gg;

        // self row (2 feats of this lane)
        unsigned int sv = xu[node * 16 + fp];
        float selfx = __uint_as_float(sv << 16);
        float selfy = __uint_as_float(sv & 0xFFFF0000u);

        float ox = 0.f, oy = 0.f;

        #pragma unroll
        for (int dir = 0; dir < 2; dir++) {
            int u = dir * N_NODES + node;
            int k0 = off[u], k1 = off[u + 1];

            // ---- gather (8-deep miss queue, identical to gather16) ----
            float a0 = 0.f, a1 = 0.f, b0 = 0.f, b1 = 0.f;
            float c0 = 0.f, c1 = 0.f, d0 = 0.f, d1 = 0.f;
            for (int p = k0; p < k1; p += 8) {
                #pragma unroll
                for (int q = 0; q < 8; q++) {
                    int kk = p + q;
                    bool act = (kk < k1);
                    int j = eidx[act ? kk : k0];
                    unsigned int v = xu[j * 16 + fp];
                    float lo = act ? __uint_as_float(v << 16) : 0.f;
                    float hi = act ? __uint_as_float(v & 0xFFFF0000u) : 0.f;
                    if ((q & 3) == 0)      { a0 += lo; a1 += hi; }
                    else if ((q & 3) == 1) { b0 += lo; b1 += hi; }
                    else if ((q & 3) == 2) { c0 += lo; c1 += hi; }
                    else                   { d0 += lo; d1 += hi; }
                }
            }
            float sx = (a0 + b0) + (c0 + d0);
            float sy = (a1 + b1) + (c1 + d1);

            // ---- h = x + agg, then input-BN (same fmaf form as dgin_mlp2) --
            float degp1 = (float)(k1 - k0 + 1);
            float hx = selfx + sx;
            float hy = selfy + sy;
            hx = fmaf(sscale[f0], hx, degp1 * sshift[f0]);
            hy = fmaf(sscale[f1], hy, degp1 * sshift[f1]);

            // ---- MLP layer 1: t1[f0,f1] = b1 + sum_i h_i * W1[i][f] -------
            float t1x = sb1[dir][f0], t1y = sb1[dir][f1];
            #pragma unroll
            for (int ii = 0; ii < 16; ii++) {
                float gx = __shfl(hx, ii, 16);   // input feat 2*ii
                float gy = __shfl(hy, ii, 16);   // input feat 2*ii+1
                float2 wx = *(const float2*)(&sW1[dir][(2 * ii) * 32 + f0]);
                float2 wy = *(const float2*)(&sW1[dir][(2 * ii + 1) * 32 + f0]);
                t1x = fmaf(gx, wx.x, t1x); t1y = fmaf(gx, wx.y, t1y);
                t1x = fmaf(gy, wy.x, t1x); t1y = fmaf(gy, wy.y, t1y);
            }
            t1x = fmaxf(t1x, 0.f); t1y = fmaxf(t1y, 0.f);

            // ---- MLP layer 2 ----
            float o2x = sb2[dir][f0], o2y = sb2[dir][f1];
            #pragma unroll
            for (int ii = 0; ii < 16; ii++) {
                float gx = __shfl(t1x, ii, 16);
                float gy = __shfl(t1y, ii, 16);
                float2 wx = *(const float2*)(&sW2[dir][(2 * ii) * 32 + f0]);
                float2 wy = *(const float2*)(&sW2[dir][(2 * ii + 1) * 32 + f0]);
                o2x = fmaf(gx, wx.x, o2x); o2y = fmaf(gx, wx.y, o2y);
                o2x = fmaf(gy, wy.x, o2x); o2y = fmaf(gy, wy.y, o2y);
            }
            if (dir == 0) {
                ox = fmaxf(o2x, 0.f); oy = fmaxf(o2y, 0.f);
            } else {
                ox = 0.5f * (ox + fmaxf(o2x, 0.f));
                oy = 0.5f * (oy + fmaxf(o2y, 0.f));
            }
        }

        // round once to bf16; stats accumulate the ROUNDED value
        unsigned short bx = f2bf(ox), by = f2bf(oy);
        ox = bf2f(bx); oy = bf2f(by);
        ou[node * 16 + fp] = (unsigned int)bx | ((unsigned int)by << 16);

        ss0 += ox; sq0 += ox * ox;
        ss1 += oy; sq1 += oy * oy;
    }

    // reduce the 4 node-groups of each wave (lanes i, i+16, i+32, i+48)
    ss0 += __shfl_down(ss0, 16); ss0 += __shfl_down(ss0, 32);
    ss1 += __shfl_down(ss1, 16); ss1 += __shfl_down(ss1, 32);
    sq0 += __shfl_down(sq0, 16); sq0 += __shfl_down(sq0, 32);
    sq1 += __shfl_down(sq1, 16); sq1 += __shfl_down(sq1, 32);
    if ((tid & 63) < 16) {
        atomicAdd(&sstat[f0], ss0);
        atomicAdd(&sstat[f1], ss1);
        atomicAdd(&sstat[32 + f0], sq0);
        atomicAdd(&sstat[32 + f1], sq1);
    }
    __syncthreads();
    if (tid < 64) atomicAdd(&stats[tid], sstat[tid]);
}

// ================= thread-per-node dual-direction GIN MLP + BN stats ========

template <int DIN, bool BN_IN, bool IN_BF16>
__global__ __launch_bounds__(256, 1)
void dgin_mlp2(const void* __restrict__ xin_v, const float* __restrict__ agg,
               const int* __restrict__ off,
               const float* __restrict__ in_stats,
               const float* __restrict__ in_g, const float* __restrict__ in_b,
               const float* __restrict__ W1f, const float* __restrict__ b1f,
               const float* __restrict__ W2f, const float* __restrict__ b2f,
               const float* __restrict__ W1b, const float* __restrict__ b1b,
               const float* __restrict__ W2b, const float* __restrict__ b2b,
               unsigned short* __restrict__ out, float* __restrict__ stats, int n)
{
    const float* xf = (const float*)xin_v;
    const unsigned short* xb = (const unsigned short*)xin_v;

    __shared__ __align__(16) float sW1[2][DIN * 32];
    __shared__ __align__(16) float sW2[2][32 * 32];
    __shared__ float sb1[2][32], sb2[2][32];
    __shared__ float sscale[32], sshift[32];
    __shared__ float sred[4 * 64];

    int tid = threadIdx.x;
    for (int i = tid; i < DIN * 32; i += 256) { sW1[0][i] = W1f[i]; sW1[1][i] = W1b[i]; }
    for (int i = tid; i < 32 * 32;  i += 256) { sW2[0][i] = W2f[i]; sW2[1][i] = W2b[i]; }
    if (tid < 32) {
        sb1[0][tid] = b1f[tid]; sb1[1][tid] = b1b[tid];
        sb2[0][tid] = b2f[tid]; sb2[1][tid] = b2b[tid];
        if (BN_IN) {
            float mu  = in_stats[tid] * INV_N;
            float var = in_stats[32 + tid] * INV_N - mu * mu;
            float sc  = in_g[tid] * rsqrtf(var + BN_EPS);
            sscale[tid] = sc;
            sshift[tid] = in_b[tid] - mu * sc;
        } else { sscale[tid] = 1.f; sshift[tid] = 0.f; }
    }
    __syncthreads();

    int n0 = blockIdx.x * 256 + tid;
    bool valid = (n0 < n);
    int node = valid ? n0 : (n - 1);

    // self row
    float xr[DIN];
    if (IN_BF16) {
        const uint4* xp = (const uint4*)(xb + node * 32);
        #pragma unroll
        for (int q = 0; q < 4; q++) {
            uint4 u = xp[q];
            unsigned int w[4] = {u.x, u.y, u.z, u.w};
            #pragma unroll
            for (int k = 0; k < 4; k++) {
                xr[8*q + 2*k]     = __uint_as_float(w[k] << 16);
                xr[8*q + 2*k + 1] = __uint_as_float(w[k] & 0xFFFF0000u);
            }
        }
    } else if (DIN == 32) {
        const float4* xp = (const float4*)(xf + node * 32);
        #pragma unroll
        for (int q = 0; q < 8; q++) {
            float4 w = xp[q];
            xr[4*q+0] = w.x; xr[4*q+1] = w.y; xr[4*q+2] = w.z; xr[4*q+3] = w.w;
        }
    } else {
        const float2* xp = (const float2*)(xf + node * DIN);
        #pragma unroll
        for (int q = 0; q < DIN / 2; q++) {
            float2 w = xp[q];
            xr[2*q+0] = w.x; xr[2*q+1] = w.y;
        }
    }

    float o[32];

    #pragma unroll
    for (int dir = 0; dir < 2; dir++) {
        float ag[DIN];
        if (DIN == 32) {
            const float4* ap = (const float4*)(agg + node * 64 + dir * 32);
            #pragma unroll
            for (int q = 0; q < 8; q++) {
                float4 w = ap[q];
                ag[4*q+0] = w.x; ag[4*q+1] = w.y; ag[4*q+2] = w.z; ag[4*q+3] = w.w;
            }
        } else {
            const float* ap = agg + node * (2 * DIN) + dir * DIN;
            #pragma unroll
            for (int i = 0; i < DIN; i++) ag[i] = ap[i];
        }
        int ob = dir * N_NODES + node;
        float degp1 = (float)(off[ob + 1] - off[ob] + 1);

        float t1[32];
        #pragma unroll
        for (int j = 0; j < 32; j++) t1[j] = sb1[dir][j];
        #pragma unroll
        for (int i = 0; i < DIN; i++) {
            float hv = xr[i] + ag[i];
            if (BN_IN) hv = fmaf(sscale[i], hv, degp1 * sshift[i]);
            const float4* wr = (const float4*)(&sW1[dir][i * 32]);
            #pragma unroll
            for (int q = 0; q < 8; q++) {
                float4 w = wr[q];
                t1[4*q+0] = fmaf(hv, w.x, t1[4*q+0]);
                t1[4*q+1] = fmaf(hv, w.y, t1[4*q+1]);
                t1[4*q+2] = fmaf(hv, w.z, t1[4*q+2]);
                t1[4*q+3] = fmaf(hv, w.w, t1[4*q+3]);
            }
        }
        #pragma unroll
        for (int j = 0; j < 32; j++) t1[j] = fmaxf(t1[j], 0.f);

        float o2[32];
        #pragma unroll
        for (int j = 0; j < 32; j++) o2[j] = sb2[dir][j];
        #pragma unroll
        for (int i = 0; i < 32; i++) {
            float hv = t1[i];
            const float4* wr = (const float4*)(&sW2[dir][i * 32]);
            #pragma unroll
            for (int q = 0; q < 8; q++) {
                float4 w = wr[q];
                o2[4*q+0] = fmaf(hv, w.x, o2[4*q+0]);
                o2[4*q+1] = fmaf(hv, w.y, o2[4*q+1]);
                o2[4*q+2] = fmaf(hv, w.z, o2[4*q+2]);
                o2[4*q+3] = fmaf(hv, w.w, o2[4*q+3]);
            }
        }
        if (dir == 0) {
            #pragma unroll
            for (int j = 0; j < 32; j++) o[j] = fmaxf(o2[j], 0.f);
        } else {
            #pragma unroll
            for (int j = 0; j < 32; j++) o[j] = 0.5f * (o[j] + fmaxf(o2[j], 0.f));
        }
    }

    // round once to bf16; stats accumulate the ROUNDED value
    #pragma unroll
    for (int j = 0; j < 32; j++) o[j] = bf2f(f2bf(o[j]));

    if (valid) {
        uint4* op = (uint4*)(out + node * 32);
        #pragma unroll
        for (int q = 0; q < 4; q++) {
            uint4 u;
            u.x = (unsigned int)f2bf(o[8*q+0]) | ((unsigned int)f2bf(o[8*q+1]) << 16);
            u.y = (unsigned int)f2bf(o[8*q+2]) | ((unsigned int)f2bf(o[8*q+3]) << 16);
            u.z = (unsigned int)f2bf(o[8*q+4]) | ((unsigned int)f2bf(o[8*q+5]) << 16);
            u.w = (unsigned int)f2bf(o[8*q+6]) | ((unsigned int)f2bf(o[8*q+7]) << 16);
            op[q] = u;
        }
    }

    int lane = tid & 63;
    int wave = tid >> 6;
    #pragma unroll
    for (int f = 0; f < 32; f++) {
        float v = valid ? o[f] : 0.f;
        float v2 = v * v;
        #pragma unroll
        for (int offs = 32; offs > 0; offs >>= 1) {
            v  += __shfl_down(v, offs);
            v2 += __shfl_down(v2, offs);
        }
        if (lane == 0) {
            sred[wave * 64 + f]      = v;
            sred[wave * 64 + 32 + f] = v2;
        }
    }
    __syncthreads();
    if (tid < 64) {
        float a = sred[tid] + sred[64 + tid] + sred[128 + tid] + sred[192 + tid];
        atomicAdd(&stats[tid], a);
    }
}

// ================= segmented mean-pool (batch is sorted) + head =============

__global__ void pool_seg(const unsigned short* __restrict__ h, const int* __restrict__ batch,
                         float* __restrict__ psum, float* __restrict__ pcnt, int n)
{
    int tid = threadIdx.x;
    int grp = tid >> 5, f = tid & 31;
    int base = blockIdx.x * 256;
    float acc = 0.f, cnt = 0.f;
    int curg = -1;
    for (int it = 0; it < 32; it++) {
        int nd = base + grp + it * 8;
        if (nd < n) {
            int g = batch[nd];
            if (g != curg) {
                if (curg >= 0) {
                    atomicAdd(&psum[curg * 32 + f], acc);
                    if (f == 0) atomicAdd(&pcnt[curg], cnt);
                }
                curg = g; acc = 0.f; cnt = 0.f;
            }
            acc += bf2f(h[nd * 32 + f]);
            cnt += 1.f;
        }
    }
    if (curg >= 0) {
        atomicAdd(&psum[curg * 32 + f], acc);
        if (f == 0) atomicAdd(&pcnt[curg], cnt);
    }
}

__global__ void head_kernel(const float* __restrict__ psum, const float* __restrict__ pcnt,
                            const float* __restrict__ stats3,
                            const float* __restrict__ g3, const float* __restrict__ b3,
                            const float* __restrict__ lbW, const float* __restrict__ lbb,
                            const float* __restrict__ lmW, const float* __restrict__ lmb,
                            float* __restrict__ out)
{
    int g = threadIdx.x;  // 512 threads, one block
    float cnt = fmaxf(pcnt[g], 1.0f);
    float inv = 1.0f / cnt;
    float p[32];
    #pragma unroll
    for (int i = 0; i < 32; i++) {
        float mu  = stats3[i] * INV_N;
        float var = stats3[32 + i] * INV_N - mu * mu;
        float a   = g3[i] * rsqrtf(var + BN_EPS);
        float b   = b3[i] - mu * a;
        p[i] = fmaf(a, psum[g * 32 + i] * inv, b);
    }
    float z = lmb[0];
    #pragma unroll
    for (int k = 0; k < 16; k++) {
        float acc = lbb[k];
        #pragma unroll
        for (int i = 0; i < 32; i++) acc += p[i] * lbW[i * 16 + k];
        z += fmaxf(acc, 0.0f) * lmW[k];
    }
    out[g] = 1.0f / (1.0f + expf(-z));
}

// ================= launcher =================================================

extern "C" void kernel_launch(void* const* d_in, const int* in_sizes, int n_in,
                              void* d_out, int out_size, void* d_ws, size_t ws_size,
                              hipStream_t stream)
{
    const float* x   = (const float*)d_in[0];
    const int* ei    = (const int*)d_in[1];
    const int* batch = (const int*)d_in[2];
    const int* src = ei;
    const int* dst = ei + N_EDGES;
    char* ws = (char*)d_ws;

    auto W = [&](int l, int j) { return (const float*)d_in[3 + (l - 1) * 10 + j]; };

    // ---------------- layout (R0 layout; h2 reuses agg region, which is dead
    // after mlp2's last agg read -- the fused layer 3 needs no agg) ----------
    unsigned short* h = (unsigned short*)(ws + 0);   // 16 MB (bf16 N x 32)
    float* xpad = (float*)(ws + 16000016);     // 8 MB (N x 8 fp32, padded x)
    float* agg  = (float*)(ws + 32000000);     // 64 MB (N x 64 fp32, F|B)
    int*   eidx = (int*)  (ws + 96000000);     // 20 MB
    int*   off  = (int*)  (ws + 116000000);    // (NT+1) ints
    // CSR-build temps live inside the agg region (dead until first gather)
    int*   deg   = (int*)  (ws + 32000000);    // 2 MB
    int*   excl  = (int*)  (ws + 34000016);    // 2 MB
    int*   bsum  = (int*)  (ws + 36000016);    // ~2 KB
    int*   boff  = (int*)  (ws + 36004016);    // ~2 KB
    int*   rank  = (int*)  (ws + 38000016);    // 10 MB packed rF|rB<<16
    // fused layer-3 output: inside agg region, written only AFTER mlp2's
    // final agg read (agg dead from then on)
    unsigned short* h2 = (unsigned short*)(ws + 48000016);  // 16 MB
    float* stats1 = (float*)(ws + 118000016);
    float* stats2 = stats1 + 64;
    float* stats3 = stats1 + 128;
    float* psum   = (float*)(ws + 118000784);
    float* pcnt   = (float*)(ws + 118066320);

    // ---- CSR build: rank pass (atomics) -> scan -> atomic-free compact fill
    hipMemsetAsync(deg, 0, NT * 4, stream);
    k_rank<<<(N_EDGES + 255) / 256, 256, 0, stream>>>(src, dst, deg, rank, N_EDGES);
    int nb = (NT + 1023) / 1024;
    scan1<<<nb, 256, 0, stream>>>(deg, excl, bsum, NT);
    scan2<<<1, 512, 0, stream>>>(bsum, boff, nb);
    scan3<<<(NT + 256) / 256, 256, 0, stream>>>(excl, boff, off, NT);
    k_fill2<<<(N_EDGES + 255) / 256, 256, 0, stream>>>(src, dst, off, rank, eidx, N_EDGES);

    pad_x<<<(N_NODES * 4 + 255) / 256, 256, 0, stream>>>(x, xpad, N_NODES);
    hipMemsetAsync(stats1, 0, 3 * 64 * 4, stream);

    const int GG   = 4096;
    const int NG64 = (N_NODES + 63) / 64;    // 3907 groups (packed layer-1)
    const int NG16 = N_NODES / 16;           // 15625 groups (exact)
    const int GM   = (N_NODES + 255) / 256;  // 977 mlp blocks (thread-per-node)

    // layer 1 (DIN=6): packed gather on xpad; mlp reads original fp32 x
    gather6p<<<GG, 256, 0, stream>>>(xpad, off, eidx, agg, NG64);
    dgin_mlp2<6, false, false><<<GM, 256, 0, stream>>>(
        x, agg, off, nullptr, nullptr, nullptr,
        W(1,0), W(1,1), W(1,2), W(1,3), W(1,4), W(1,5), W(1,6), W(1,7),
        h, stats1, N_NODES);

    // layer 2 (R0 path, the A of the A/B): gather -> agg -> mlp, h in place
    gather16<<<GG, 256, 0, stream>>>(h, off, eidx, agg, NG16);
    dgin_mlp2<32, true, true><<<GM, 256, 0, stream>>>(
        h, agg, off, stats1, W(1,8), W(1,9),
        W(2,0), W(2,1), W(2,2), W(2,3), W(2,4), W(2,5), W(2,6), W(2,7),
        h, stats2, N_NODES);

    // layer 3 (the B): fused gather+MLP at (256,4), h -> h2 (not in place)
    dgin_fused<<<GG, 256, 0, stream>>>(
        h, off, eidx, stats2, W(2,8), W(2,9),
        W(3,0), W(3,1), W(3,2), W(3,3), W(3,4), W(3,5), W(3,6), W(3,7),
        h2, stats3, NG16);

    hipMemsetAsync(psum, 0, (size_t)N_GRAPHS * 32 * 4, stream);
    hipMemsetAsync(pcnt, 0, (size_t)N_GRAPHS * 4, stream);
    pool_seg<<<(N_NODES + 255) / 256, 256, 0, stream>>>(h2, batch, psum, pcnt, N_NODES);
    head_kernel<<<1, 512, 0, stream>>>(psum, pcnt, stats3, W(3,8), W(3,9),
        (const float*)d_in[33], (const float*)d_in[34],
        (const float*)d_in[35], (const float*)d_in[36],
        (float*)d_out);
}

// Round 4
// 974.946 us; speedup vs baseline: 3.2887x; 2.0100x over previous
//
#include <hip/hip_runtime.h>
#include <math.h>

#define N_NODES 250000
#define N_EDGES 2500000
#define N_GRAPHS 512
#define BN_EPS 1e-5f
#define NT 500000   // 2*N_NODES degree/offset slots (F then B)
#define INV_N (1.0f / (float)N_NODES)

// bf16 helpers (RNE); bf16->fp32 is an exact bit shift.
__device__ __forceinline__ unsigned short f2bf(float x) {
    unsigned int u = __float_as_uint(x);
    unsigned int r = (u + 0x7FFFu + ((u >> 16) & 1u)) >> 16;
    return (unsigned short)r;
}
__device__ __forceinline__ float bf2f(unsigned short b) {
    return __uint_as_float(((unsigned int)b) << 16);
}

// ================= CSR build (R0 structure: rank -> scan -> compact fill) ===
// R1 lesson: sparse bucket scatter churns partial-line writebacks (+260us).
// R2/R3 lesson: gather+MLP fusion is latency-bound by structure (serialized
// shfl MLP phases starve the miss queue) -- keep gather and MLP separate.
// k_rank's 5M returning atomics (32B write-through each, 166MB @ ~810GB/s)
// are the irreducible floor of this build (~205us).

__global__ void k_rank(const int* __restrict__ src, const int* __restrict__ dst,
                       int* __restrict__ deg, int* __restrict__ rank, int E)
{
    int e = blockIdx.x * blockDim.x + threadIdx.x;
    if (e >= E) return;
    int rF = atomicAdd(&deg[dst[e]], 1);            // F lists keyed by dst
    int rB = atomicAdd(&deg[N_NODES + src[e]], 1);  // B lists keyed by src
    rank[e] = rF | (rB << 16);
}

__global__ void k_fill2(const int* __restrict__ src, const int* __restrict__ dst,
                        const int* __restrict__ off, const int* __restrict__ rank,
                        int* __restrict__ eidx, int E)
{
    int e = blockIdx.x * blockDim.x + threadIdx.x;
    if (e >= E) return;
    int s = src[e], d = dst[e];
    int r = rank[e];
    eidx[off[d] + (r & 0xFFFF)] = s;
    eidx[off[N_NODES + s] + (r >> 16)] = d;
}

__global__ void scan1(const int* __restrict__ deg, int* __restrict__ excl,
                      int* __restrict__ bsum, int n)
{
    __shared__ int s[256];
    int t = threadIdx.x, b = blockIdx.x;
    int base = b * 1024 + t * 4;
    int v[4]; int tsum = 0;
    #pragma unroll
    for (int i = 0; i < 4; i++) { v[i] = (base + i < n) ? deg[base + i] : 0; tsum += v[i]; }
    s[t] = tsum; __syncthreads();
    for (int o = 1; o < 256; o <<= 1) {
        int x = (t >= o) ? s[t - o] : 0; __syncthreads();
        s[t] += x; __syncthreads();
    }
    int run = s[t] - tsum;
    #pragma unroll
    for (int i = 0; i < 4; i++) { if (base + i < n) excl[base + i] = run; run += v[i]; }
    if (t == 255) bsum[b] = s[255];
}

__global__ void scan2(const int* __restrict__ bsum, int* __restrict__ boff, int nb)
{
    __shared__ int s[512];
    int t = threadIdx.x;
    int v = (t < nb) ? bsum[t] : 0;
    s[t] = v; __syncthreads();
    for (int o = 1; o < 512; o <<= 1) {
        int x = (t >= o) ? s[t - o] : 0; __syncthreads();
        s[t] += x; __syncthreads();
    }
    if (t < nb) boff[t] = s[t] - v;
}

__global__ void scan3(const int* __restrict__ excl, const int* __restrict__ boff,
                      int* __restrict__ off, int n)
{
    int i = blockIdx.x * blockDim.x + threadIdx.x;
    if (i < n) off[i] = excl[i] + boff[i >> 10];
    if (i == 0) off[n] = 2 * N_EDGES;
}

// ================= pad x (N x 6 fp32) -> xpad (N x 8 fp32) ==================

__global__ void pad_x(const float* __restrict__ x, float* __restrict__ xpad, int n)
{
    int i = blockIdx.x * blockDim.x + threadIdx.x;   // one float2 out per thread
    if (i >= n * 4) return;
    int node = i >> 2, p2 = i & 3;
    float2 v;
    v.x = (2 * p2     < 6) ? x[node * 6 + 2 * p2]     : 0.f;
    v.y = (2 * p2 + 1 < 6) ? x[node * 6 + 2 * p2 + 1] : 0.f;
    *(float2*)(xpad + node * 8 + 2 * p2) = v;
}

// ============ layer-1 gather, PACKED: 4 lanes x float2 per padded row =======

__global__ __launch_bounds__(256, 8)
void gather6p(const float* __restrict__ xpad, const int* __restrict__ off,
              const int* __restrict__ eidx, float* __restrict__ agg, int ngroups)
{
    int tid = threadIdx.x;
    int p2   = tid & 3;       // float2 index within row (cols 2p2, 2p2+1)
    int slot = tid >> 2;      // 0..63 node slots per block
    for (int grp = blockIdx.x; grp < ngroups; grp += gridDim.x) {
        int node = grp * 64 + slot;
        bool nvalid = (node < N_NODES);
        int nd = nvalid ? node : 0;
        #pragma unroll
        for (int dir = 0; dir < 2; dir++) {
            int u = dir * N_NODES + nd;
            int k0 = off[u], k1 = off[u + 1];
            if (!nvalid) k1 = k0;
            float a0=0.f,a1=0.f,b0=0.f,b1=0.f,c0=0.f,c1=0.f,d0=0.f,d1=0.f;
            for (int p = k0; p < k1; p += 8) {
                #pragma unroll
                for (int q = 0; q < 8; q++) {
                    int kk = p + q;
                    bool act = (kk < k1);
                    int j = eidx[act ? kk : k0];
                    float2 v = *(const float2*)(xpad + j * 8 + 2 * p2);
                    float lo = act ? v.x : 0.f;
                    float hi = act ? v.y : 0.f;
                    if ((q & 3) == 0)      { a0 += lo; a1 += hi; }
                    else if ((q & 3) == 1) { b0 += lo; b1 += hi; }
                    else if ((q & 3) == 2) { c0 += lo; c1 += hi; }
                    else                   { d0 += lo; d1 += hi; }
                }
            }
            if (nvalid && p2 < 3) {
                float2 s;
                s.x = (a0 + b0) + (c0 + d0);
                s.y = (a1 + b1) + (c1 + d1);
                *(float2*)(agg + nd * 12 + dir * 6 + 2 * p2) = s;
            }
        }
    }
}

// ================= bf16 gather (DIN=32): ushort2 per lane, 16 lanes/row =====
// 8-deep queue, (256,8). Layer-2 variant (A of the A/B).

__global__ __launch_bounds__(256, 8)
void gather16(const unsigned short* __restrict__ xb, const int* __restrict__ off,
              const int* __restrict__ eidx, float* __restrict__ agg, int ngroups)
{
    const unsigned int* xu = (const unsigned int*)xb;   // row = 16 uints
    int tid = threadIdx.x;
    int fp = tid & 15;
    int gg = tid >> 4;
    for (int grp = blockIdx.x; grp < ngroups; grp += gridDim.x) {
        int node = grp * 16 + gg;
        #pragma unroll
        for (int dir = 0; dir < 2; dir++) {
            int u = dir * N_NODES + node;
            int k0 = off[u], k1 = off[u + 1];
            float a0 = 0.f, a1 = 0.f, b0 = 0.f, b1 = 0.f;
            float c0 = 0.f, c1 = 0.f, d0 = 0.f, d1 = 0.f;
            for (int p = k0; p < k1; p += 8) {
                #pragma unroll
                for (int q = 0; q < 8; q++) {
                    int kk = p + q;
                    bool act = (kk < k1);
                    int j = eidx[act ? kk : k0];
                    unsigned int v = xu[j * 16 + fp];
                    float lo = act ? __uint_as_float(v << 16) : 0.f;
                    float hi = act ? __uint_as_float(v & 0xFFFF0000u) : 0.f;
                    if ((q & 3) == 0)      { a0 += lo; a1 += hi; }
                    else if ((q & 3) == 1) { b0 += lo; b1 += hi; }
                    else if ((q & 3) == 2) { c0 += lo; c1 += hi; }
                    else                   { d0 += lo; d1 += hi; }
                }
            }
            float2 s;
            s.x = (a0 + b0) + (c0 + d0);
            s.y = (a1 + b1) + (c1 + d1);
            *(float2*)(agg + node * 64 + dir * 32 + 2 * fp) = s;
        }
    }
}

// 12-deep queue variant, (256,6) cap 42 (B of the A/B on miss-queue depth).

__global__ __launch_bounds__(256, 6)
void gather16_12(const unsigned short* __restrict__ xb, const int* __restrict__ off,
                 const int* __restrict__ eidx, float* __restrict__ agg, int ngroups)
{
    const unsigned int* xu = (const unsigned int*)xb;
    int tid = threadIdx.x;
    int fp = tid & 15;
    int gg = tid >> 4;
    for (int grp = blockIdx.x; grp < ngroups; grp += gridDim.x) {
        int node = grp * 16 + gg;
        #pragma unroll
        for (int dir = 0; dir < 2; dir++) {
            int u = dir * N_NODES + node;
            int k0 = off[u], k1 = off[u + 1];
            float a0 = 0.f, a1 = 0.f, b0 = 0.f, b1 = 0.f;
            float c0 = 0.f, c1 = 0.f, d0 = 0.f, d1 = 0.f;
            for (int p = k0; p < k1; p += 12) {
                #pragma unroll
                for (int q = 0; q < 12; q++) {
                    int kk = p + q;
                    bool act = (kk < k1);
                    int j = eidx[act ? kk : k0];
                    unsigned int v = xu[j * 16 + fp];
                    float lo = act ? __uint_as_float(v << 16) : 0.f;
                    float hi = act ? __uint_as_float(v & 0xFFFF0000u) : 0.f;
                    if ((q & 3) == 0)      { a0 += lo; a1 += hi; }
                    else if ((q & 3) == 1) { b0 += lo; b1 += hi; }
                    else if ((q & 3) == 2) { c0 += lo; c1 += hi; }
                    else                   { d0 += lo; d1 += hi; }
                }
            }
            float2 s;
            s.x = (a0 + b0) + (c0 + d0);
            s.y = (a1 + b1) + (c1 + d1);
            *(float2*)(agg + node * 64 + dir * 32 + 2 * fp) = s;
        }
    }
}

// ================= thread-per-node dual-direction GIN MLP + BN stats ========
// R4 change (the ONLY change vs R0): __launch_bounds__(256,1) -> (256,2).
// Live-register accounting peaks at ~150-170 VGPR (xr[32]+ag[32]+o[32]+
// t1[32]+temps), so the 256-VGPR budget of (256,2) should be spill-free and
// raise occupancy from ~1 to 2-3 blocks/CU for the 96MB/layer streaming.
// No-spill check: mlp2 WRITE_SIZE must stay ~17MB/dispatch.

template <int DIN, bool BN_IN, bool IN_BF16>
__global__ __launch_bounds__(256, 2)
void dgin_mlp2(const void* __restrict__ xin_v, const float* __restrict__ agg,
               const int* __restrict__ off,
               const float* __restrict__ in_stats,
               const float* __restrict__ in_g, const float* __restrict__ in_b,
               const float* __restrict__ W1f, const float* __restrict__ b1f,
               const float* __restrict__ W2f, const float* __restrict__ b2f,
               const float* __restrict__ W1b, const float* __restrict__ b1b,
               const float* __restrict__ W2b, const float* __restrict__ b2b,
               unsigned short* __restrict__ out, float* __restrict__ stats, int n)
{
    const float* xf = (const float*)xin_v;
    const unsigned short* xb = (const unsigned short*)xin_v;

    __shared__ __align__(16) float sW1[2][DIN * 32];
    __shared__ __align__(16) float sW2[2][32 * 32];
    __shared__ float sb1[2][32], sb2[2][32];
    __shared__ float sscale[32], sshift[32];
    __shared__ float sred[4 * 64];

    int tid = threadIdx.x;
    for (int i = tid; i < DIN * 32; i += 256) { sW1[0][i] = W1f[i]; sW1[1][i] = W1b[i]; }
    for (int i = tid; i < 32 * 32;  i += 256) { sW2[0][i] = W2f[i]; sW2[1][i] = W2b[i]; }
    if (tid < 32) {
        sb1[0][tid] = b1f[tid]; sb1[1][tid] = b1b[tid];
        sb2[0][tid] = b2f[tid]; sb2[1][tid] = b2b[tid];
        if (BN_IN) {
            float mu  = in_stats[tid] * INV_N;
            float var = in_stats[32 + tid] * INV_N - mu * mu;
            float sc  = in_g[tid] * rsqrtf(var + BN_EPS);
            sscale[tid] = sc;
            sshift[tid] = in_b[tid] - mu * sc;
        } else { sscale[tid] = 1.f; sshift[tid] = 0.f; }
    }
    __syncthreads();

    int n0 = blockIdx.x * 256 + tid;
    bool valid = (n0 < n);
    int node = valid ? n0 : (n - 1);

    // self row
    float xr[DIN];
    if (IN_BF16) {
        const uint4* xp = (const uint4*)(xb + node * 32);
        #pragma unroll
        for (int q = 0; q < 4; q++) {
            uint4 u = xp[q];
            unsigned int w[4] = {u.x, u.y, u.z, u.w};
            #pragma unroll
            for (int k = 0; k < 4; k++) {
                xr[8*q + 2*k]     = __uint_as_float(w[k] << 16);
                xr[8*q + 2*k + 1] = __uint_as_float(w[k] & 0xFFFF0000u);
            }
        }
    } else if (DIN == 32) {
        const float4* xp = (const float4*)(xf + node * 32);
        #pragma unroll
        for (int q = 0; q < 8; q++) {
            float4 w = xp[q];
            xr[4*q+0] = w.x; xr[4*q+1] = w.y; xr[4*q+2] = w.z; xr[4*q+3] = w.w;
        }
    } else {
        const float2* xp = (const float2*)(xf + node * DIN);
        #pragma unroll
        for (int q = 0; q < DIN / 2; q++) {
            float2 w = xp[q];
            xr[2*q+0] = w.x; xr[2*q+1] = w.y;
        }
    }

    float o[32];

    #pragma unroll
    for (int dir = 0; dir < 2; dir++) {
        float ag[DIN];
        if (DIN == 32) {
            const float4* ap = (const float4*)(agg + node * 64 + dir * 32);
            #pragma unroll
            for (int q = 0; q < 8; q++) {
                float4 w = ap[q];
                ag[4*q+0] = w.x; ag[4*q+1] = w.y; ag[4*q+2] = w.z; ag[4*q+3] = w.w;
            }
        } else {
            const float* ap = agg + node * (2 * DIN) + dir * DIN;
            #pragma unroll
            for (int i = 0; i < DIN; i++) ag[i] = ap[i];
        }
        int ob = dir * N_NODES + node;
        float degp1 = (float)(off[ob + 1] - off[ob] + 1);

        float t1[32];
        #pragma unroll
        for (int j = 0; j < 32; j++) t1[j] = sb1[dir][j];
        #pragma unroll
        for (int i = 0; i < DIN; i++) {
            float hv = xr[i] + ag[i];
            if (BN_IN) hv = fmaf(sscale[i], hv, degp1 * sshift[i]);
            const float4* wr = (const float4*)(&sW1[dir][i * 32]);
            #pragma unroll
            for (int q = 0; q < 8; q++) {
                float4 w = wr[q];
                t1[4*q+0] = fmaf(hv, w.x, t1[4*q+0]);
                t1[4*q+1] = fmaf(hv, w.y, t1[4*q+1]);
                t1[4*q+2] = fmaf(hv, w.z, t1[4*q+2]);
                t1[4*q+3] = fmaf(hv, w.w, t1[4*q+3]);
            }
        }
        #pragma unroll
        for (int j = 0; j < 32; j++) t1[j] = fmaxf(t1[j], 0.f);

        float o2[32];
        #pragma unroll
        for (int j = 0; j < 32; j++) o2[j] = sb2[dir][j];
        #pragma unroll
        for (int i = 0; i < 32; i++) {
            float hv = t1[i];
            const float4* wr = (const float4*)(&sW2[dir][i * 32]);
            #pragma unroll
            for (int q = 0; q < 8; q++) {
                float4 w = wr[q];
                o2[4*q+0] = fmaf(hv, w.x, o2[4*q+0]);
                o2[4*q+1] = fmaf(hv, w.y, o2[4*q+1]);
                o2[4*q+2] = fmaf(hv, w.z, o2[4*q+2]);
                o2[4*q+3] = fmaf(hv, w.w, o2[4*q+3]);
            }
        }
        if (dir == 0) {
            #pragma unroll
            for (int j = 0; j < 32; j++) o[j] = fmaxf(o2[j], 0.f);
        } else {
            #pragma unroll
            for (int j = 0; j < 32; j++) o[j] = 0.5f * (o[j] + fmaxf(o2[j], 0.f));
        }
    }

    // round once to bf16; stats accumulate the ROUNDED value
    #pragma unroll
    for (int j = 0; j < 32; j++) o[j] = bf2f(f2bf(o[j]));

    if (valid) {
        uint4* op = (uint4*)(out + node * 32);
        #pragma unroll
        for (int q = 0; q < 4; q++) {
            uint4 u;
            u.x = (unsigned int)f2bf(o[8*q+0]) | ((unsigned int)f2bf(o[8*q+1]) << 16);
            u.y = (unsigned int)f2bf(o[8*q+2]) | ((unsigned int)f2bf(o[8*q+3]) << 16);
            u.z = (unsigned int)f2bf(o[8*q+4]) | ((unsigned int)f2bf(o[8*q+5]) << 16);
            u.w = (unsigned int)f2bf(o[8*q+6]) | ((unsigned int)f2bf(o[8*q+7]) << 16);
            op[q] = u;
        }
    }

    int lane = tid & 63;
    int wave = tid >> 6;
    #pragma unroll
    for (int f = 0; f < 32; f++) {
        float v = valid ? o[f] : 0.f;
        float v2 = v * v;
        #pragma unroll
        for (int offs = 32; offs > 0; offs >>= 1) {
            v  += __shfl_down(v, offs);
            v2 += __shfl_down(v2, offs);
        }
        if (lane == 0) {
            sred[wave * 64 + f]      = v;
            sred[wave * 64 + 32 + f] = v2;
        }
    }
    __syncthreads();
    if (tid < 64) {
        float a = sred[tid] + sred[64 + tid] + sred[128 + tid] + sred[192 + tid];
        atomicAdd(&stats[tid], a);
    }
}

// ================= segmented mean-pool (batch is sorted) + head =============

__global__ void pool_seg(const unsigned short* __restrict__ h, const int* __restrict__ batch,
                         float* __restrict__ psum, float* __restrict__ pcnt, int n)
{
    int tid = threadIdx.x;
    int grp = tid >> 5, f = tid & 31;
    int base = blockIdx.x * 256;
    float acc = 0.f, cnt = 0.f;
    int curg = -1;
    for (int it = 0; it < 32; it++) {
        int nd = base + grp + it * 8;
        if (nd < n) {
            int g = batch[nd];
            if (g != curg) {
                if (curg >= 0) {
                    atomicAdd(&psum[curg * 32 + f], acc);
                    if (f == 0) atomicAdd(&pcnt[curg], cnt);
                }
                curg = g; acc = 0.f; cnt = 0.f;
            }
            acc += bf2f(h[nd * 32 + f]);
            cnt += 1.f;
        }
    }
    if (curg >= 0) {
        atomicAdd(&psum[curg * 32 + f], acc);
        if (f == 0) atomicAdd(&pcnt[curg], cnt);
    }
}

__global__ void head_kernel(const float* __restrict__ psum, const float* __restrict__ pcnt,
                            const float* __restrict__ stats3,
                            const float* __restrict__ g3, const float* __restrict__ b3,
                            const float* __restrict__ lbW, const float* __restrict__ lbb,
                            const float* __restrict__ lmW, const float* __restrict__ lmb,
                            float* __restrict__ out)
{
    int g = threadIdx.x;  // 512 threads, one block
    float cnt = fmaxf(pcnt[g], 1.0f);
    float inv = 1.0f / cnt;
    float p[32];
    #pragma unroll
    for (int i = 0; i < 32; i++) {
        float mu  = stats3[i] * INV_N;
        float var = stats3[32 + i] * INV_N - mu * mu;
        float a   = g3[i] * rsqrtf(var + BN_EPS);
        float b   = b3[i] - mu * a;
        p[i] = fmaf(a, psum[g * 32 + i] * inv, b);
    }
    float z = lmb[0];
    #pragma unroll
    for (int k = 0; k < 16; k++) {
        float acc = lbb[k];
        #pragma unroll
        for (int i = 0; i < 32; i++) acc += p[i] * lbW[i * 16 + k];
        z += fmaxf(acc, 0.0f) * lmW[k];
    }
    out[g] = 1.0f / (1.0f + expf(-z));
}

// ================= launcher =================================================

extern "C" void kernel_launch(void* const* d_in, const int* in_sizes, int n_in,
                              void* d_out, int out_size, void* d_ws, size_t ws_size,
                              hipStream_t stream)
{
    const float* x   = (const float*)d_in[0];
    const int* ei    = (const int*)d_in[1];
    const int* batch = (const int*)d_in[2];
    const int* src = ei;
    const int* dst = ei + N_EDGES;
    char* ws = (char*)d_ws;

    auto W = [&](int l, int j) { return (const float*)d_in[3 + (l - 1) * 10 + j]; };

    // ---------------- layout ----------------
    unsigned short* h = (unsigned short*)(ws + 0);   // 16 MB (bf16 N x 32)
    float* xpad = (float*)(ws + 16000016);     // 8 MB (N x 8 fp32, padded x)
    float* agg  = (float*)(ws + 32000000);     // 64 MB (N x 64 fp32, interleaved F|B)
    int*   eidx = (int*)  (ws + 96000000);     // 20 MB
    int*   off  = (int*)  (ws + 116000000);    // (NT+1) ints
    // CSR-build temps live inside the agg region (dead until first gather)
    int*   deg   = (int*)  (ws + 32000000);    // 2 MB
    int*   excl  = (int*)  (ws + 34000016);    // 2 MB
    int*   bsum  = (int*)  (ws + 36000016);    // ~2 KB
    int*   boff  = (int*)  (ws + 36004016);    // ~2 KB
    int*   rank  = (int*)  (ws + 38000016);    // 10 MB packed rF|rB<<16
    float* stats1 = (float*)(ws + 118000016);
    float* stats2 = stats1 + 64;
    float* stats3 = stats1 + 128;
    float* psum   = (float*)(ws + 118000784);
    float* pcnt   = (float*)(ws + 118066320);

    // ---- CSR build: rank pass (atomics) -> scan -> atomic-free fill
    hipMemsetAsync(deg, 0, NT * 4, stream);
    k_rank<<<(N_EDGES + 255) / 256, 256, 0, stream>>>(src, dst, deg, rank, N_EDGES);
    int nb = (NT + 1023) / 1024;
    scan1<<<nb, 256, 0, stream>>>(deg, excl, bsum, NT);
    scan2<<<1, 512, 0, stream>>>(bsum, boff, nb);
    scan3<<<(NT + 256) / 256, 256, 0, stream>>>(excl, boff, off, NT);
    k_fill2<<<(N_EDGES + 255) / 256, 256, 0, stream>>>(src, dst, off, rank, eidx, N_EDGES);

    pad_x<<<(N_NODES * 4 + 255) / 256, 256, 0, stream>>>(x, xpad, N_NODES);
    hipMemsetAsync(stats1, 0, 3 * 64 * 4, stream);

    const int GG   = 4096;
    const int NG64 = (N_NODES + 63) / 64;    // 3907 groups (packed layer-1)
    const int NG16 = N_NODES / 16;           // 15625 groups (bf16 gather16)
    const int GM   = (N_NODES + 255) / 256;  // 977 mlp blocks (thread-per-node)

    // layer 1 (DIN=6): packed gather on xpad; mlp reads original fp32 x
    gather6p<<<GG, 256, 0, stream>>>(xpad, off, eidx, agg, NG64);
    dgin_mlp2<6, false, false><<<GM, 256, 0, stream>>>(
        x, agg, off, nullptr, nullptr, nullptr,
        W(1,0), W(1,1), W(1,2), W(1,3), W(1,4), W(1,5), W(1,6), W(1,7),
        h, stats1, N_NODES);

    // layer 2: 8-deep gather (A)
    gather16<<<GG, 256, 0, stream>>>(h, off, eidx, agg, NG16);
    dgin_mlp2<32, true, true><<<GM, 256, 0, stream>>>(
        h, agg, off, stats1, W(1,8), W(1,9),
        W(2,0), W(2,1), W(2,2), W(2,3), W(2,4), W(2,5), W(2,6), W(2,7),
        h, stats2, N_NODES);

    // layer 3: 12-deep gather (B) — within-round A/B vs layer 2
    gather16_12<<<GG, 256, 0, stream>>>(h, off, eidx, agg, NG16);
    dgin_mlp2<32, true, true><<<GM, 256, 0, stream>>>(
        h, agg, off, stats2, W(2,8), W(2,9),
        W(3,0), W(3,1), W(3,2), W(3,3), W(3,4), W(3,5), W(3,6), W(3,7),
        h, stats3, N_NODES);

    hipMemsetAsync(psum, 0, (size_t)N_GRAPHS * 32 * 4, stream);
    hipMemsetAsync(pcnt, 0, (size_t)N_GRAPHS * 4, stream);
    pool_seg<<<(N_NODES + 255) / 256, 256, 0, stream>>>(h, batch, psum, pcnt, N_NODES);
    head_kernel<<<1, 512, 0, stream>>>(psum, pcnt, stats3, W(3,8), W(3,9),
        (const float*)d_in[33], (const float*)d_in[34],
        (const float*)d_in[35], (const float*)d_in[36],
        (float*)d_out);
}

// Round 5
// 808.147 us; speedup vs baseline: 3.9675x; 1.2064x over previous
//
#include <hip/hip_runtime.h>
#include <math.h>

#define N_NODES 250000
#define N_EDGES 2500000
#define N_GRAPHS 512
#define BN_EPS 1e-5f
#define NT 500000   // 2*N_NODES offset slots (F then B)
#define INV_N (1.0f / (float)N_NODES)
#define NBUCK 245   // ceil(N_NODES / 1024)
#define BSHIFT 10

// bf16 helpers (RNE); bf16->fp32 is an exact bit shift.
__device__ __forceinline__ unsigned short f2bf(float x) {
    unsigned int u = __float_as_uint(x);
    unsigned int r = (u + 0x7FFFu + ((u >> 16) & 1u)) >> 16;
    return (unsigned short)r;
}
__device__ __forceinline__ float bf2f(unsigned short b) {
    return __uint_as_float(((unsigned int)b) << 16);
}

// ============== CSR build v3: two-level LDS bucket sort =====================
// R0: 5M device atomic-returns (k_rank) = 200us @ 25G/s RMW wall.
// R1: sparse bucket scatter = partial-line churn. R5: move the per-node RMWs
// into LDS. Coarse-bucket (node>>10, 245 buckets) partition with per-block
// LDS histograms (300k global atomics), then one block per bucket counts/
// scans/scatters its 1024 nodes entirely in LDS. off[] values produced are
// IDENTICAL to the old build; list order differs (tolerance-OK, R1 evidence).

// A1: global bucket totals via per-block LDS histogram.
__global__ __launch_bounds__(256)
void k_histA(const int* __restrict__ src, const int* __restrict__ dst,
             int* __restrict__ gcnt, int E)
{
    __shared__ int hF[256], hB[256];
    int t = threadIdx.x;
    hF[t] = 0; hB[t] = 0;
    __syncthreads();
    for (int e = blockIdx.x * 256 + t; e < E; e += gridDim.x * 256) {
        atomicAdd(&hF[dst[e] >> BSHIFT], 1);
        atomicAdd(&hB[src[e] >> BSHIFT], 1);
    }
    __syncthreads();
    if (hF[t]) atomicAdd(&gcnt[t], hF[t]);
    if (hB[t]) atomicAdd(&gcnt[256 + t], hB[t]);
}

// scan bucket totals -> region starts + cursors; also off[NT].
__global__ void k_scanBk(const int* __restrict__ gcnt,
                         int* __restrict__ bOffF, int* __restrict__ bOffB,
                         int* __restrict__ cursF, int* __restrict__ cursB,
                         int* __restrict__ off)
{
    __shared__ int s[512];
    int t = threadIdx.x;   // 256
    int vF = (t < NBUCK) ? gcnt[t] : 0;
    int vB = (t < NBUCK) ? gcnt[256 + t] : 0;
    s[t] = vF; s[256 + t] = vB;
    __syncthreads();
    for (int o = 1; o < 256; o <<= 1) {
        int xF = (t >= o) ? s[t - o] : 0;
        int xB = (t >= o) ? s[256 + t - o] : 0;
        __syncthreads();
        s[t] += xF; s[256 + t] += xB;
        __syncthreads();
    }
    int exF = s[t] - vF;
    int exB = s[256 + t] - vB;
    if (t < NBUCK) {
        bOffF[t] = exF; cursF[t] = exF;
        bOffB[t] = exB; cursB[t] = exB;
    }
    if (t == 0) {
        bOffF[NBUCK] = N_EDGES;
        bOffB[NBUCK] = N_EDGES;
        off[NT] = 2 * N_EDGES;
    }
}

// A2: chunk-reserve per (block,bucket), scatter packed (nodeLow<<18)|nbr.
__global__ __launch_bounds__(256)
void k_scatA(const int* __restrict__ src, const int* __restrict__ dst,
             int* __restrict__ cursF, int* __restrict__ cursB,
             unsigned int* __restrict__ payF, unsigned int* __restrict__ payB, int E)
{
    __shared__ int hF[256], hB[256];
    __shared__ int cF[256], cB[256];
    int t = threadIdx.x;
    hF[t] = 0; hB[t] = 0;
    __syncthreads();
    int e0 = blockIdx.x * 256 + t, STR = gridDim.x * 256;
    for (int e = e0; e < E; e += STR) {
        atomicAdd(&hF[dst[e] >> BSHIFT], 1);
        atomicAdd(&hB[src[e] >> BSHIFT], 1);
    }
    __syncthreads();
    int baseF = 0, baseB = 0;
    if (t < NBUCK) {
        if (hF[t]) baseF = atomicAdd(&cursF[t], hF[t]);
        if (hB[t]) baseB = atomicAdd(&cursB[t], hB[t]);
    }
    __syncthreads();
    cF[t] = baseF; cB[t] = baseB;
    __syncthreads();
    for (int e = e0; e < E; e += STR) {
        int s = src[e], d = dst[e];
        int tf = atomicAdd(&cF[d >> BSHIFT], 1);
        payF[tf] = ((unsigned int)(d & 1023) << 18) | (unsigned int)s;
        int tb = atomicAdd(&cB[s >> BSHIFT], 1);
        payB[tb] = ((unsigned int)(s & 1023) << 18) | (unsigned int)d;
    }
}

// Level 2: one block per (bucket, dir): LDS count -> LDS scan -> off write ->
// LDS-cursor scatter into compact eidx.
__global__ __launch_bounds__(256)
void k_bucket(const unsigned int* __restrict__ payF, const unsigned int* __restrict__ payB,
              const int* __restrict__ bOffF, const int* __restrict__ bOffB,
              int* __restrict__ eidx, int* __restrict__ off)
{
    __shared__ int cnt[1024];
    __shared__ int ps[256];
    int blk = blockIdx.x;
    int d  = (blk >= NBUCK) ? 1 : 0;
    int bb = blk - d * NBUCK;
    const unsigned int* pay = d ? payB : payF;
    const int* bOff = d ? bOffB : bOffF;
    int t = threadIdx.x;
    int lo = bOff[bb], hi = bOff[bb + 1];

    #pragma unroll
    for (int k = 0; k < 4; k++) cnt[t + 256 * k] = 0;
    __syncthreads();
    for (int e = lo + t; e < hi; e += 256)
        atomicAdd(&cnt[pay[e] >> 18], 1);
    __syncthreads();

    int b4 = 4 * t;
    int v0 = cnt[b4], v1 = cnt[b4 + 1], v2 = cnt[b4 + 2], v3 = cnt[b4 + 3];
    int tsum = v0 + v1 + v2 + v3;
    ps[t] = tsum;
    __syncthreads();
    for (int o = 1; o < 256; o <<= 1) {
        int x = (t >= o) ? ps[t - o] : 0;
        __syncthreads();
        ps[t] += x;
        __syncthreads();
    }
    int run = ps[t] - tsum;
    int l0 = run, l1 = run + v0, l2 = run + v0 + v1, l3 = run + v0 + v1 + v2;
    cnt[b4] = l0; cnt[b4 + 1] = l1; cnt[b4 + 2] = l2; cnt[b4 + 3] = l3;

    int gbase = d * N_EDGES + lo;
    int node0 = bb * 1024 + b4;
    if (node0 + 0 < N_NODES) off[d * N_NODES + node0 + 0] = gbase + l0;
    if (node0 + 1 < N_NODES) off[d * N_NODES + node0 + 1] = gbase + l1;
    if (node0 + 2 < N_NODES) off[d * N_NODES + node0 + 2] = gbase + l2;
    if (node0 + 3 < N_NODES) off[d * N_NODES + node0 + 3] = gbase + l3;
    __syncthreads();

    for (int e = lo + t; e < hi; e += 256) {
        unsigned int p = pay[e];
        int r = atomicAdd(&cnt[p >> 18], 1);
        eidx[gbase + r] = (int)(p & 0x3FFFFu);
    }
}

// ================= pad x (N x 6 fp32) -> xpad (N x 8 fp32) ==================

__global__ void pad_x(const float* __restrict__ x, float* __restrict__ xpad, int n)
{
    int i = blockIdx.x * blockDim.x + threadIdx.x;   // one float2 out per thread
    if (i >= n * 4) return;
    int node = i >> 2, p2 = i & 3;
    float2 v;
    v.x = (2 * p2     < 6) ? x[node * 6 + 2 * p2]     : 0.f;
    v.y = (2 * p2 + 1 < 6) ? x[node * 6 + 2 * p2 + 1] : 0.f;
    *(float2*)(xpad + node * 8 + 2 * p2) = v;
}

// ============ layer-1 gather, PACKED: 4 lanes x float2 per padded row =======

__global__ __launch_bounds__(256, 8)
void gather6p(const float* __restrict__ xpad, const int* __restrict__ off,
              const int* __restrict__ eidx, float* __restrict__ agg, int ngroups)
{
    int tid = threadIdx.x;
    int p2   = tid & 3;       // float2 index within row (cols 2p2, 2p2+1)
    int slot = tid >> 2;      // 0..63 node slots per block
    for (int grp = blockIdx.x; grp < ngroups; grp += gridDim.x) {
        int node = grp * 64 + slot;
        bool nvalid = (node < N_NODES);
        int nd = nvalid ? node : 0;
        #pragma unroll
        for (int dir = 0; dir < 2; dir++) {
            int u = dir * N_NODES + nd;
            int k0 = off[u], k1 = off[u + 1];
            if (!nvalid) k1 = k0;
            float a0=0.f,a1=0.f,b0=0.f,b1=0.f,c0=0.f,c1=0.f,d0=0.f,d1=0.f;
            for (int p = k0; p < k1; p += 8) {
                #pragma unroll
                for (int q = 0; q < 8; q++) {
                    int kk = p + q;
                    bool act = (kk < k1);
                    int j = eidx[act ? kk : k0];
                    float2 v = *(const float2*)(xpad + j * 8 + 2 * p2);
                    float lo = act ? v.x : 0.f;
                    float hi = act ? v.y : 0.f;
                    if ((q & 3) == 0)      { a0 += lo; a1 += hi; }
                    else if ((q & 3) == 1) { b0 += lo; b1 += hi; }
                    else if ((q & 3) == 2) { c0 += lo; c1 += hi; }
                    else                   { d0 += lo; d1 += hi; }
                }
            }
            if (nvalid && p2 < 3) {
                float2 s;
                s.x = (a0 + b0) + (c0 + d0);
                s.y = (a1 + b1) + (c1 + d1);
                *(float2*)(agg + nd * 12 + dir * 6 + 2 * p2) = s;
            }
        }
    }
}

// ================= bf16 gather (DIN=32): ushort2 per lane, 16 lanes/row =====
// 8-deep queue, (256,8). Layer-2 variant (A of the A/B).

__global__ __launch_bounds__(256, 8)
void gather16(const unsigned short* __restrict__ xb, const int* __restrict__ off,
              const int* __restrict__ eidx, float* __restrict__ agg, int ngroups)
{
    const unsigned int* xu = (const unsigned int*)xb;   // row = 16 uints
    int tid = threadIdx.x;
    int fp = tid & 15;
    int gg = tid >> 4;
    for (int grp = blockIdx.x; grp < ngroups; grp += gridDim.x) {
        int node = grp * 16 + gg;
        #pragma unroll
        for (int dir = 0; dir < 2; dir++) {
            int u = dir * N_NODES + node;
            int k0 = off[u], k1 = off[u + 1];
            float a0 = 0.f, a1 = 0.f, b0 = 0.f, b1 = 0.f;
            float c0 = 0.f, c1 = 0.f, d0 = 0.f, d1 = 0.f;
            for (int p = k0; p < k1; p += 8) {
                #pragma unroll
                for (int q = 0; q < 8; q++) {
                    int kk = p + q;
                    bool act = (kk < k1);
                    int j = eidx[act ? kk : k0];
                    unsigned int v = xu[j * 16 + fp];
                    float lo = act ? __uint_as_float(v << 16) : 0.f;
                    float hi = act ? __uint_as_float(v & 0xFFFF0000u) : 0.f;
                    if ((q & 3) == 0)      { a0 += lo; a1 += hi; }
                    else if ((q & 3) == 1) { b0 += lo; b1 += hi; }
                    else if ((q & 3) == 2) { c0 += lo; c1 += hi; }
                    else                   { d0 += lo; d1 += hi; }
                }
            }
            float2 s;
            s.x = (a0 + b0) + (c0 + d0);
            s.y = (a1 + b1) + (c1 + d1);
            *(float2*)(agg + node * 64 + dir * 32 + 2 * fp) = s;
        }
    }
}

// 12-deep queue variant, (256,6) cap 42 (B of the A/B on miss-queue depth).

__global__ __launch_bounds__(256, 6)
void gather16_12(const unsigned short* __restrict__ xb, const int* __restrict__ off,
                 const int* __restrict__ eidx, float* __restrict__ agg, int ngroups)
{
    const unsigned int* xu = (const unsigned int*)xb;
    int tid = threadIdx.x;
    int fp = tid & 15;
    int gg = tid >> 4;
    for (int grp = blockIdx.x; grp < ngroups; grp += gridDim.x) {
        int node = grp * 16 + gg;
        #pragma unroll
        for (int dir = 0; dir < 2; dir++) {
            int u = dir * N_NODES + node;
            int k0 = off[u], k1 = off[u + 1];
            float a0 = 0.f, a1 = 0.f, b0 = 0.f, b1 = 0.f;
            float c0 = 0.f, c1 = 0.f, d0 = 0.f, d1 = 0.f;
            for (int p = k0; p < k1; p += 12) {
                #pragma unroll
                for (int q = 0; q < 12; q++) {
                    int kk = p + q;
                    bool act = (kk < k1);
                    int j = eidx[act ? kk : k0];
                    unsigned int v = xu[j * 16 + fp];
                    float lo = act ? __uint_as_float(v << 16) : 0.f;
                    float hi = act ? __uint_as_float(v & 0xFFFF0000u) : 0.f;
                    if ((q & 3) == 0)      { a0 += lo; a1 += hi; }
                    else if ((q & 3) == 1) { b0 += lo; b1 += hi; }
                    else if ((q & 3) == 2) { c0 += lo; c1 += hi; }
                    else                   { d0 += lo; d1 += hi; }
                }
            }
            float2 s;
            s.x = (a0 + b0) + (c0 + d0);
            s.y = (a1 + b1) + (c1 + d1);
            *(float2*)(agg + node * 64 + dir * 32 + 2 * fp) = s;
        }
    }
}

// ================= thread-per-node dual-direction GIN MLP + BN stats ========
// R4 win: (256,2) -> 2-3 blocks/CU, no spill.

template <int DIN, bool BN_IN, bool IN_BF16>
__global__ __launch_bounds__(256, 2)
void dgin_mlp2(const void* __restrict__ xin_v, const float* __restrict__ agg,
               const int* __restrict__ off,
               const float* __restrict__ in_stats,
               const float* __restrict__ in_g, const float* __restrict__ in_b,
               const float* __restrict__ W1f, const float* __restrict__ b1f,
               const float* __restrict__ W2f, const float* __restrict__ b2f,
               const float* __restrict__ W1b, const float* __restrict__ b1b,
               const float* __restrict__ W2b, const float* __restrict__ b2b,
               unsigned short* __restrict__ out, float* __restrict__ stats, int n)
{
    const float* xf = (const float*)xin_v;
    const unsigned short* xb = (const unsigned short*)xin_v;

    __shared__ __align__(16) float sW1[2][DIN * 32];
    __shared__ __align__(16) float sW2[2][32 * 32];
    __shared__ float sb1[2][32], sb2[2][32];
    __shared__ float sscale[32], sshift[32];
    __shared__ float sred[4 * 64];

    int tid = threadIdx.x;
    for (int i = tid; i < DIN * 32; i += 256) { sW1[0][i] = W1f[i]; sW1[1][i] = W1b[i]; }
    for (int i = tid; i < 32 * 32;  i += 256) { sW2[0][i] = W2f[i]; sW2[1][i] = W2b[i]; }
    if (tid < 32) {
        sb1[0][tid] = b1f[tid]; sb1[1][tid] = b1b[tid];
        sb2[0][tid] = b2f[tid]; sb2[1][tid] = b2b[tid];
        if (BN_IN) {
            float mu  = in_stats[tid] * INV_N;
            float var = in_stats[32 + tid] * INV_N - mu * mu;
            float sc  = in_g[tid] * rsqrtf(var + BN_EPS);
            sscale[tid] = sc;
            sshift[tid] = in_b[tid] - mu * sc;
        } else { sscale[tid] = 1.f; sshift[tid] = 0.f; }
    }
    __syncthreads();

    int n0 = blockIdx.x * 256 + tid;
    bool valid = (n0 < n);
    int node = valid ? n0 : (n - 1);

    // self row
    float xr[DIN];
    if (IN_BF16) {
        const uint4* xp = (const uint4*)(xb + node * 32);
        #pragma unroll
        for (int q = 0; q < 4; q++) {
            uint4 u = xp[q];
            unsigned int w[4] = {u.x, u.y, u.z, u.w};
            #pragma unroll
            for (int k = 0; k < 4; k++) {
                xr[8*q + 2*k]     = __uint_as_float(w[k] << 16);
                xr[8*q + 2*k + 1] = __uint_as_float(w[k] & 0xFFFF0000u);
            }
        }
    } else if (DIN == 32) {
        const float4* xp = (const float4*)(xf + node * 32);
        #pragma unroll
        for (int q = 0; q < 8; q++) {
            float4 w = xp[q];
            xr[4*q+0] = w.x; xr[4*q+1] = w.y; xr[4*q+2] = w.z; xr[4*q+3] = w.w;
        }
    } else {
        const float2* xp = (const float2*)(xf + node * DIN);
        #pragma unroll
        for (int q = 0; q < DIN / 2; q++) {
            float2 w = xp[q];
            xr[2*q+0] = w.x; xr[2*q+1] = w.y;
        }
    }

    float o[32];

    #pragma unroll
    for (int dir = 0; dir < 2; dir++) {
        float ag[DIN];
        if (DIN == 32) {
            const float4* ap = (const float4*)(agg + node * 64 + dir * 32);
            #pragma unroll
            for (int q = 0; q < 8; q++) {
                float4 w = ap[q];
                ag[4*q+0] = w.x; ag[4*q+1] = w.y; ag[4*q+2] = w.z; ag[4*q+3] = w.w;
            }
        } else {
            const float* ap = agg + node * (2 * DIN) + dir * DIN;
            #pragma unroll
            for (int i = 0; i < DIN; i++) ag[i] = ap[i];
        }
        int ob = dir * N_NODES + node;
        float degp1 = (float)(off[ob + 1] - off[ob] + 1);

        float t1[32];
        #pragma unroll
        for (int j = 0; j < 32; j++) t1[j] = sb1[dir][j];
        #pragma unroll
        for (int i = 0; i < DIN; i++) {
            float hv = xr[i] + ag[i];
            if (BN_IN) hv = fmaf(sscale[i], hv, degp1 * sshift[i]);
            const float4* wr = (const float4*)(&sW1[dir][i * 32]);
            #pragma unroll
            for (int q = 0; q < 8; q++) {
                float4 w = wr[q];
                t1[4*q+0] = fmaf(hv, w.x, t1[4*q+0]);
                t1[4*q+1] = fmaf(hv, w.y, t1[4*q+1]);
                t1[4*q+2] = fmaf(hv, w.z, t1[4*q+2]);
                t1[4*q+3] = fmaf(hv, w.w, t1[4*q+3]);
            }
        }
        #pragma unroll
        for (int j = 0; j < 32; j++) t1[j] = fmaxf(t1[j], 0.f);

        float o2[32];
        #pragma unroll
        for (int j = 0; j < 32; j++) o2[j] = sb2[dir][j];
        #pragma unroll
        for (int i = 0; i < 32; i++) {
            float hv = t1[i];
            const float4* wr = (const float4*)(&sW2[dir][i * 32]);
            #pragma unroll
            for (int q = 0; q < 8; q++) {
                float4 w = wr[q];
                o2[4*q+0] = fmaf(hv, w.x, o2[4*q+0]);
                o2[4*q+1] = fmaf(hv, w.y, o2[4*q+1]);
                o2[4*q+2] = fmaf(hv, w.z, o2[4*q+2]);
                o2[4*q+3] = fmaf(hv, w.w, o2[4*q+3]);
            }
        }
        if (dir == 0) {
            #pragma unroll
            for (int j = 0; j < 32; j++) o[j] = fmaxf(o2[j], 0.f);
        } else {
            #pragma unroll
            for (int j = 0; j < 32; j++) o[j] = 0.5f * (o[j] + fmaxf(o2[j], 0.f));
        }
    }

    // round once to bf16; stats accumulate the ROUNDED value
    #pragma unroll
    for (int j = 0; j < 32; j++) o[j] = bf2f(f2bf(o[j]));

    if (valid) {
        uint4* op = (uint4*)(out + node * 32);
        #pragma unroll
        for (int q = 0; q < 4; q++) {
            uint4 u;
            u.x = (unsigned int)f2bf(o[8*q+0]) | ((unsigned int)f2bf(o[8*q+1]) << 16);
            u.y = (unsigned int)f2bf(o[8*q+2]) | ((unsigned int)f2bf(o[8*q+3]) << 16);
            u.z = (unsigned int)f2bf(o[8*q+4]) | ((unsigned int)f2bf(o[8*q+5]) << 16);
            u.w = (unsigned int)f2bf(o[8*q+6]) | ((unsigned int)f2bf(o[8*q+7]) << 16);
            op[q] = u;
        }
    }

    int lane = tid & 63;
    int wave = tid >> 6;
    #pragma unroll
    for (int f = 0; f < 32; f++) {
        float v = valid ? o[f] : 0.f;
        float v2 = v * v;
        #pragma unroll
        for (int offs = 32; offs > 0; offs >>= 1) {
            v  += __shfl_down(v, offs);
            v2 += __shfl_down(v2, offs);
        }
        if (lane == 0) {
            sred[wave * 64 + f]      = v;
            sred[wave * 64 + 32 + f] = v2;
        }
    }
    __syncthreads();
    if (tid < 64) {
        float a = sred[tid] + sred[64 + tid] + sred[128 + tid] + sred[192 + tid];
        atomicAdd(&stats[tid], a);
    }
}

// ================= segmented mean-pool (batch is sorted) + head =============

__global__ void pool_seg(const unsigned short* __restrict__ h, const int* __restrict__ batch,
                         float* __restrict__ psum, float* __restrict__ pcnt, int n)
{
    int tid = threadIdx.x;
    int grp = tid >> 5, f = tid & 31;
    int base = blockIdx.x * 256;
    float acc = 0.f, cnt = 0.f;
    int curg = -1;
    for (int it = 0; it < 32; it++) {
        int nd = base + grp + it * 8;
        if (nd < n) {
            int g = batch[nd];
            if (g != curg) {
                if (curg >= 0) {
                    atomicAdd(&psum[curg * 32 + f], acc);
                    if (f == 0) atomicAdd(&pcnt[curg], cnt);
                }
                curg = g; acc = 0.f; cnt = 0.f;
            }
            acc += bf2f(h[nd * 32 + f]);
            cnt += 1.f;
        }
    }
    if (curg >= 0) {
        atomicAdd(&psum[curg * 32 + f], acc);
        if (f == 0) atomicAdd(&pcnt[curg], cnt);
    }
}

__global__ void head_kernel(const float* __restrict__ psum, const float* __restrict__ pcnt,
                            const float* __restrict__ stats3,
                            const float* __restrict__ g3, const float* __restrict__ b3,
                            const float* __restrict__ lbW, const float* __restrict__ lbb,
                            const float* __restrict__ lmW, const float* __restrict__ lmb,
                            float* __restrict__ out)
{
    int g = threadIdx.x;  // 512 threads, one block
    float cnt = fmaxf(pcnt[g], 1.0f);
    float inv = 1.0f / cnt;
    float p[32];
    #pragma unroll
    for (int i = 0; i < 32; i++) {
        float mu  = stats3[i] * INV_N;
        float var = stats3[32 + i] * INV_N - mu * mu;
        float a   = g3[i] * rsqrtf(var + BN_EPS);
        float b   = b3[i] - mu * a;
        p[i] = fmaf(a, psum[g * 32 + i] * inv, b);
    }
    float z = lmb[0];
    #pragma unroll
    for (int k = 0; k < 16; k++) {
        float acc = lbb[k];
        #pragma unroll
        for (int i = 0; i < 32; i++) acc += p[i] * lbW[i * 16 + k];
        z += fmaxf(acc, 0.0f) * lmW[k];
    }
    out[g] = 1.0f / (1.0f + expf(-z));
}

// ================= launcher =================================================

extern "C" void kernel_launch(void* const* d_in, const int* in_sizes, int n_in,
                              void* d_out, int out_size, void* d_ws, size_t ws_size,
                              hipStream_t stream)
{
    const float* x   = (const float*)d_in[0];
    const int* ei    = (const int*)d_in[1];
    const int* batch = (const int*)d_in[2];
    const int* src = ei;
    const int* dst = ei + N_EDGES;
    char* ws = (char*)d_ws;

    auto W = [&](int l, int j) { return (const float*)d_in[3 + (l - 1) * 10 + j]; };

    // ---------------- layout ----------------
    unsigned short* h = (unsigned short*)(ws + 0);   // 16 MB (bf16 N x 32)
    float* xpad = (float*)(ws + 16000016);     // 8 MB (N x 8 fp32, padded x)
    float* agg  = (float*)(ws + 32000000);     // 64 MB (N x 64 fp32, F|B)
    int*   eidx = (int*)  (ws + 96000000);     // 20 MB
    int*   off  = (int*)  (ws + 116000000);    // (NT+1) ints
    // CSR-build temps inside the agg region (all dead before gather6p)
    int* gcnt  = (int*)(ws + 32000000);        // 512 ints
    int* bOffF = (int*)(ws + 32002048);        // NBUCK+1
    int* bOffB = (int*)(ws + 32003072);        // NBUCK+1
    int* cursF = (int*)(ws + 32004096);        // NBUCK
    int* cursB = (int*)(ws + 32005120);        // NBUCK
    unsigned int* payF = (unsigned int*)(ws + 32008192);  // 10 MB
    unsigned int* payB = (unsigned int*)(ws + 42008192);  // 10 MB
    float* stats1 = (float*)(ws + 118000016);
    float* stats2 = stats1 + 64;
    float* stats3 = stats1 + 128;
    float* psum   = (float*)(ws + 118000784);
    float* pcnt   = (float*)(ws + 118066320);

    // ---- CSR build v3: LDS bucket sort (no per-node device atomics)
    hipMemsetAsync(gcnt, 0, 2048, stream);
    k_histA<<<1024, 256, 0, stream>>>(src, dst, gcnt, N_EDGES);
    k_scanBk<<<1, 256, 0, stream>>>(gcnt, bOffF, bOffB, cursF, cursB, off);
    k_scatA<<<384, 256, 0, stream>>>(src, dst, cursF, cursB, payF, payB, N_EDGES);
    k_bucket<<<2 * NBUCK, 256, 0, stream>>>(payF, payB, bOffF, bOffB, eidx, off);

    pad_x<<<(N_NODES * 4 + 255) / 256, 256, 0, stream>>>(x, xpad, N_NODES);
    hipMemsetAsync(stats1, 0, 3 * 64 * 4, stream);

    const int GG   = 4096;
    const int NG64 = (N_NODES + 63) / 64;    // 3907 groups (packed layer-1)
    const int NG16 = N_NODES / 16;           // 15625 groups (bf16 gather16)
    const int GM   = (N_NODES + 255) / 256;  // 977 mlp blocks (thread-per-node)

    // layer 1 (DIN=6): packed gather on xpad; mlp reads original fp32 x
    gather6p<<<GG, 256, 0, stream>>>(xpad, off, eidx, agg, NG64);
    dgin_mlp2<6, false, false><<<GM, 256, 0, stream>>>(
        x, agg, off, nullptr, nullptr, nullptr,
        W(1,0), W(1,1), W(1,2), W(1,3), W(1,4), W(1,5), W(1,6), W(1,7),
        h, stats1, N_NODES);

    // layer 2: 8-deep gather (A)
    gather16<<<GG, 256, 0, stream>>>(h, off, eidx, agg, NG16);
    dgin_mlp2<32, true, true><<<GM, 256, 0, stream>>>(
        h, agg, off, stats1, W(1,8), W(1,9),
        W(2,0), W(2,1), W(2,2), W(2,3), W(2,4), W(2,5), W(2,6), W(2,7),
        h, stats2, N_NODES);

    // layer 3: 12-deep gather (B)
    gather16_12<<<GG, 256, 0, stream>>>(h, off, eidx, agg, NG16);
    dgin_mlp2<32, true, true><<<GM, 256, 0, stream>>>(
        h, agg, off, stats2, W(2,8), W(2,9),
        W(3,0), W(3,1), W(3,2), W(3,3), W(3,4), W(3,5), W(3,6), W(3,7),
        h, stats3, N_NODES);

    hipMemsetAsync(psum, 0, (size_t)N_GRAPHS * 32 * 4, stream);
    hipMemsetAsync(pcnt, 0, (size_t)N_GRAPHS * 4, stream);
    pool_seg<<<(N_NODES + 255) / 256, 256, 0, stream>>>(h, batch, psum, pcnt, N_NODES);
    head_kernel<<<1, 512, 0, stream>>>(psum, pcnt, stats3, W(3,8), W(3,9),
        (const float*)d_in[33], (const float*)d_in[34],
        (const float*)d_in[35], (const float*)d_in[36],
        (float*)d_out);
}